// Round 14
// baseline (209.852 us; speedup 1.0000x reference)
//
#include <hip/hip_runtime.h>
#include <math.h>

#define NTOK 65536
#define LSEQ 16384
#define GCH 64
#define NCH 256   // LSEQ / GCH

typedef __attribute__((ext_vector_type(8))) short short8v;
typedef __attribute__((ext_vector_type(4))) float f32x4;
typedef unsigned short u16;

__device__ __forceinline__ u16 f2bf(float f) {
  unsigned u = __float_as_uint(f);
  return (u16)((u + 0x7FFFu + ((u >> 16) & 1u)) >> 16);
}
__device__ __forceinline__ float bf2f(u16 b) {
  return __uint_as_float(((unsigned)b) << 16);
}
__device__ __forceinline__ unsigned cvtpk_bf16(float lo, float hi) {
  unsigned r;
  asm("v_cvt_pk_bf16_f32 %0, %1, %2" : "=v"(r) : "v"(lo), "v"(hi));
  return r;
}
__device__ __forceinline__ float silu_f(float v) {
  return v * __builtin_amdgcn_rcpf(1.f + __expf(-v));
}
__device__ __forceinline__ void gld16(const u16* g, u16* l) {
  __builtin_amdgcn_global_load_lds((const __attribute__((address_space(1))) void*)g,
                                   (__attribute__((address_space(3))) void*)l, 16, 0, 0);
}

#define WAITV2 asm volatile("s_waitcnt vmcnt(2) lgkmcnt(0)" ::: "memory")
#define WAITV1 asm volatile("s_waitcnt vmcnt(1) lgkmcnt(0)" ::: "memory")
#define WAITV0 asm volatile("s_waitcnt vmcnt(0) lgkmcnt(0)" ::: "memory")
#define BARRAW asm volatile("s_barrier" ::: "memory")

// ---------------- K0a: scalar SSM parameter setup (fp64) ----------------
__global__ void setup_scalar_k(const float* __restrict__ A_real, const float* __restrict__ A_imag,
                               const float* __restrict__ inv_dt,
                               float2* __restrict__ dAf, float2* __restrict__ fvec,
                               float2* __restrict__ powt) {
  int p = threadIdx.x;
  if (p >= 64) return;
  double ar = (double)A_real[p], ai = (double)A_imag[p];
  double dt = log1p(exp((double)inv_dt[p]));   // softplus
  double zr = 0.5 * dt * ar, zi = 0.5 * dt * ai;
  double d1r = 1.0 - zr;
  double den = d1r * d1r + zi * zi;
  double blr = d1r / den, bli = zi / den;      // BL = 1/(1-z)
  double nr = 1.0 + zr, ni = zi;               // 1+z
  double dar = blr * nr - bli * ni;            // dA
  double dai = blr * ni + bli * nr;
  dAf[p] = make_float2((float)dar, (float)dai);
  fvec[p] = make_float2((float)(blr * dt), (float)(bli * dt));   // f = BL*dt
  double cr = 1.0, ci = 0.0;
  for (int k = 0; k <= GCH; ++k) {
    powt[p * (GCH + 1) + k] = make_float2((float)cr, (float)ci); // dA^k
    double t = cr * dar - ci * dai;
    ci = cr * dai + ci * dar;
    cr = t;
  }
}

// ---------------- K0b: build bf16 B^T-layout weight tables ----------------
__global__ void setup_tables_k(const float* __restrict__ B_re, const float* __restrict__ B_im,
                               const float* __restrict__ C_re, const float* __restrict__ C_im,
                               const float* __restrict__ W_in, const float* __restrict__ W_out,
                               const float2* __restrict__ fvec,
                               u16* __restrict__ WinT, u16* __restrict__ dBn,
                               u16* __restrict__ Ccb, u16* __restrict__ WoutT) {
  int idx = blockIdx.x * blockDim.x + threadIdx.x;
  int stride = gridDim.x * blockDim.x;
  // WinT [1024][256]
  for (int i = idx; i < 1024 * 256; i += stride) {
    int n = i >> 8, k = i & 255;
    WinT[i] = f2bf(W_in[k * 1024 + n]);
  }
  // dBn [128][512]  (rows 0-63 Re(dB), 64-127 Im(dB))
  for (int i = idx; i < 128 * 512; i += stride) {
    int p = i >> 9, d = i & 511;
    float2 f = fvec[p & 63];
    float br = B_re[(p & 63) * 512 + d], bi = B_im[(p & 63) * 512 + d];
    float v = (p < 64) ? (f.x * br - f.y * bi) : (f.x * bi + f.y * br);
    dBn[i] = f2bf(v);
  }
  // Ccb [512][128]  (cols 0-63: C_re, 64-127: -C_im)
  for (int i = idx; i < 512 * 128; i += stride) {
    int d = i >> 7, k = i & 127;
    float v = (k < 64) ? C_re[d * 64 + k] : -C_im[d * 64 + (k - 64)];
    Ccb[i] = f2bf(v);
  }
  // WoutT [256][512]
  for (int i = idx; i < 256 * 512; i += stride) {
    int n = i >> 9, k = i & 511;
    WoutT[i] = f2bf(W_out[k * 256 + n]);
  }
}

// ---------------- x -> bf16 ----------------
__global__ __launch_bounds__(256) void cvt_x_k(const float* __restrict__ x, u16* __restrict__ xb) {
  size_t i = ((size_t)blockIdx.x * blockDim.x + threadIdx.x) * 4;
  size_t stride = (size_t)gridDim.x * blockDim.x * 4;
  const size_t total = (size_t)NTOK * 256;
  for (; i < total; i += stride) {
    float4 v = *(const float4*)(x + i);
    ushort4 o;
    o.x = f2bf(v.x); o.y = f2bf(v.y); o.z = f2bf(v.z); o.w = f2bf(v.w);
    *(ushort4*)(xb + i) = o;
  }
}

// ---------------- K1: [u|res] = silu(xb @ WinT) — LDS-coalesced epilogue -------
// 8 waves (2x4), 128x128 tile, BK=32, NT=8, gld_lds both operands, 3 LDS bufs,
// depth-2 counted vmcnt(2). Epilogue scratch stride 148 u16: 4-row step =
// 296 dwords = 8 mod 32 banks -> write groups at offsets 0/8/16/24 (conflict-
// free; stride 144 was 0 mod 32 = 8-way, 2.6M conflicts in R13).
__global__ __launch_bounds__(512) void k1_gemm(
    const u16* __restrict__ A, const u16* __restrict__ Bt,
    u16* __restrict__ u_bf, u16* __restrict__ sr_bf) {
  constexpr int KDIM = 256, NT = 8;
  __shared__ u16 lds[24576];             // 48 KB: As[3] | Bs[3]; scratch aliases
  u16* AsB = lds;
  u16* BsB = lds + 12288;
  const int tid = threadIdx.x;
  const int w = tid >> 6, l = tid & 63;
  const int wm = w >> 2, wn = w & 3;

  const int lin = blockIdx.x;
  const int cpx = gridDim.x >> 3;
  const int swz = (lin & 7) * cpx + (lin >> 3);
  const int n0 = (swz & 7) * 128;
  const int m0 = (swz >> 3) * 128;

  f32x4 acc[4][2] = {};

  const int lr = l >> 2;
  const int sc = (l & 3) ^ ((l >> 3) & 3);
  const u16* gA = A + (size_t)(m0 + w * 16 + lr) * KDIM + sc * 8;
  const u16* gB = Bt + (size_t)(n0 + w * 16 + lr) * KDIM + sc * 8;

  const int fr = l & 15;
  const int kgs = (((l >> 4) ^ (l >> 1)) & 3) * 8;

  auto stage = [&](int buf, int k0) {
    gld16(gA + k0, &AsB[buf * 4096 + w * 512]);
    gld16(gB + k0, &BsB[buf * 4096 + w * 512]);
  };
  auto compute = [&](int buf) {
    short8v af[4], bfr[2];
#pragma unroll
    for (int mi = 0; mi < 4; ++mi)
      af[mi] = *(const short8v*)&AsB[buf * 4096 + (wm * 64 + mi * 16 + fr) * 32 + kgs];
#pragma unroll
    for (int ni = 0; ni < 2; ++ni)
      bfr[ni] = *(const short8v*)&BsB[buf * 4096 + (wn * 32 + ni * 16 + fr) * 32 + kgs];
#pragma unroll
    for (int mi = 0; mi < 4; ++mi)
#pragma unroll
      for (int ni = 0; ni < 2; ++ni)
        acc[mi][ni] = __builtin_amdgcn_mfma_f32_16x16x32_bf16(af[mi], bfr[ni], acc[mi][ni], 0, 0, 0);
  };

  stage(0, 0);
  stage(1, 32);
#pragma unroll
  for (int t = 0; t < NT; ++t) {
    if (t + 1 < NT) { WAITV2; } else { WAITV0; }
    BARRAW;
    if (t + 2 < NT) stage((t + 2) % 3, (t + 2) * 32);
    compute(t % 3);
  }

  // ---- LDS-coalesced epilogue (stride 148) ----
  __syncthreads();
  u16* scr = lds;                        // 128 x 148 u16 = 37,888 B
  const int rbase = (l >> 4) * 4;
#pragma unroll
  for (int mi = 0; mi < 4; ++mi) {
#pragma unroll
    for (int ni = 0; ni < 2; ++ni) {
      int lr0 = wm * 64 + mi * 16 + rbase;
      int lc = wn * 32 + ni * 16 + fr;
      float s0 = silu_f(acc[mi][ni][0]);
      float s1 = silu_f(acc[mi][ni][1]);
      float s2 = silu_f(acc[mi][ni][2]);
      float s3 = silu_f(acc[mi][ni][3]);
      unsigned p01 = cvtpk_bf16(s0, s1);
      unsigned p23 = cvtpk_bf16(s2, s3);
      scr[(lr0 + 0) * 148 + lc] = (u16)p01;
      scr[(lr0 + 1) * 148 + lc] = (u16)(p01 >> 16);
      scr[(lr0 + 2) * 148 + lc] = (u16)p23;
      scr[(lr0 + 3) * 148 + lc] = (u16)(p23 >> 16);
    }
  }
  __syncthreads();
  u16* Cw = (n0 < 512) ? u_bf : sr_bf;
  const int cb = (n0 < 512) ? n0 : (n0 - 512);
#pragma unroll
  for (int r = 0; r < 4; ++r) {
    int row = (tid >> 4) + r * 32;
    int ch = (tid & 15) * 8;
    uint4 v = *(const uint4*)&scr[row * 148 + ch];
    *(uint4*)&Cw[(size_t)(m0 + row) * 512 + cb + ch] = v;
  }
}

// ------------- 16-wave MFMA GEMM: 128x256 tile, BK=32, 1024 threads -------------
// Waves 0-7 stage A (gld_lds), waves 8-15 stage B (2 gld_lds). 3 bufs, depth-2,
// per-wave counted vmcnt (A:1, B:2).
// MODE 2: g = (acc + D*u)*sres -> C1 via LDS-coalesced epilogue (stride 276)
// MODE 3: C0(fp32)[m*256+n] = acc via 2-pass LDS-coalesced epilogue (stride 262)
template<int MODE, int LOG_NBX, int KDIM>
__global__ __launch_bounds__(1024) void mgemm2(
    const u16* __restrict__ Ain, const u16* __restrict__ Bt,
    void* __restrict__ C0, void* __restrict__ C1,
    const float* __restrict__ Dvec) {
  constexpr int NT = KDIM / 32;
  __shared__ u16 lds[36864];             // 72 KB: As[3] | Bs[3]; scratch aliases
  u16* AsB = lds;
  u16* BsB = lds + 12288;
  const int tid = threadIdx.x;
  const int w = tid >> 6, l = tid & 63;
  const int wm = w >> 3, wn = w & 7;
  const bool isA = (w < 8);

  const int lin = blockIdx.x;
  const int cpx = gridDim.x >> 3;
  const int swz = (lin & 7) * cpx + (lin >> 3);
  const int n0 = (swz & ((1 << LOG_NBX) - 1)) * 256;
  const int m0 = (swz >> LOG_NBX) * 128;

  f32x4 acc[4][2] = {};

  const int fr = l & 15;
  const int kgs = (((l >> 4) ^ (l >> 1)) & 3) * 8;
  const int sr = l >> 2;
  const int scs = (l & 3) ^ ((l >> 3) & 3);

  const u16* gA = nullptr;
  const u16* gB = nullptr;
  if (isA) gA = Ain + (size_t)(m0 + w * 16 + sr) * KDIM + scs * 8;
  else     gB = Bt + (size_t)(n0 + (w - 8) * 16 + sr) * KDIM + scs * 8;

  auto stage = [&](int buf, int k0) {
    if (isA) {
      gld16(gA + k0, &AsB[buf * 4096 + w * 512]);
    } else {
      gld16(gB + k0, &BsB[buf * 8192 + (w - 8) * 512]);
      gld16(gB + k0 + (size_t)128 * KDIM, &BsB[buf * 8192 + (w - 8) * 512 + 4096]);
    }
  };
  auto compute = [&](int buf) {
    short8v af[4], bfr[2];
#pragma unroll
    for (int mi = 0; mi < 4; ++mi)
      af[mi] = *(const short8v*)&AsB[buf * 4096 + (wm * 64 + mi * 16 + fr) * 32 + kgs];
#pragma unroll
    for (int ni = 0; ni < 2; ++ni)
      bfr[ni] = *(const short8v*)&BsB[buf * 8192 + (wn * 32 + ni * 16 + fr) * 32 + kgs];
#pragma unroll
    for (int mi = 0; mi < 4; ++mi)
#pragma unroll
      for (int ni = 0; ni < 2; ++ni)
        acc[mi][ni] = __builtin_amdgcn_mfma_f32_16x16x32_bf16(af[mi], bfr[ni], acc[mi][ni], 0, 0, 0);
  };

  stage(0, 0);
  stage(1, 32);
#pragma unroll
  for (int t = 0; t < NT; ++t) {
    if (t + 1 < NT) { if (isA) { WAITV1; } else { WAITV2; } } else { WAITV0; }
    BARRAW;
    if (t + 2 < NT) stage((t + 2) % 3, (t + 2) * 32);
    compute(t % 3);
  }

  const int rbase = (l >> 4) * 4;
  if (MODE == 2) {
    // ---- LDS-coalesced epilogue: g tile (128x256 bf16), stride 276 ----
    __syncthreads();
    u16* scr = lds;                      // 128 x 276 u16 = 70,656 B
#pragma unroll
    for (int mi = 0; mi < 4; ++mi) {
#pragma unroll
      for (int ni = 0; ni < 2; ++ni) {
        int lr0 = wm * 64 + mi * 16 + rbase;
        int lc = wn * 32 + ni * 16 + fr;
        int gr0 = m0 + lr0;
        int gc = n0 + lc;
        float g[4];
#pragma unroll
        for (int j = 0; j < 4; ++j) {
          size_t r = (size_t)(gr0 + j);
          float uu = bf2f(((const u16*)C0)[r * 512 + gc]);
          float sr2 = bf2f(((const u16*)C1)[r * 512 + gc]);
          g[j] = (acc[mi][ni][j] + Dvec[gc] * uu) * sr2;
        }
        unsigned p01 = cvtpk_bf16(g[0], g[1]);
        unsigned p23 = cvtpk_bf16(g[2], g[3]);
        scr[(lr0 + 0) * 276 + lc] = (u16)p01;
        scr[(lr0 + 1) * 276 + lc] = (u16)(p01 >> 16);
        scr[(lr0 + 2) * 276 + lc] = (u16)p23;
        scr[(lr0 + 3) * 276 + lc] = (u16)(p23 >> 16);
      }
    }
    __syncthreads();
#pragma unroll
    for (int r = 0; r < 4; ++r) {
      int row = (tid >> 5) + r * 32;
      int ch = (tid & 31) * 8;
      uint4 v = *(const uint4*)&scr[row * 276 + ch];
      *(uint4*)&((u16*)C1)[(size_t)(m0 + row) * 512 + n0 + ch] = v;
    }
  } else {
    // ---- 2-pass LDS-coalesced fp32 epilogue (64 rows/pass, stride 262) ----
    float* scrf = (float*)lds;           // 64 x 262 f32 = 67,072 B
#pragma unroll
    for (int pass = 0; pass < 2; ++pass) {
      __syncthreads();
      if (wm == pass) {
#pragma unroll
        for (int mi = 0; mi < 4; ++mi) {
#pragma unroll
          for (int ni = 0; ni < 2; ++ni) {
            int lr0 = mi * 16 + rbase;   // row within 64-row half
            int lc = wn * 32 + ni * 16 + fr;
#pragma unroll
            for (int j = 0; j < 4; ++j)
              scrf[(lr0 + j) * 262 + lc] = acc[mi][ni][j];
          }
        }
      }
      __syncthreads();
#pragma unroll
      for (int r = 0; r < 4; ++r) {
        int row = tid >> 4;              // 0..63
        int ch = (tid & 15) * 4 + r * 64;
        float4 v = *(const float4*)&scrf[row * 262 + ch];
        *(float4*)&((float*)C0)[(size_t)(m0 + pass * 64 + row) * 256 + n0 + ch] = v;
      }
    }
  }
}

// ---------------- K2: Bu(bf16) = u @ dB^T + fused chunk carry-sum ----------
// Bu written via LDS-coalesced epilogue (stride 132); carry sums fp32.
__global__ __launch_bounds__(512) void k2_bu_carry(
    const u16* __restrict__ A, const u16* __restrict__ Bt,
    u16* __restrict__ Bu, float* __restrict__ carr, float* __restrict__ carr2,
    const float2* __restrict__ dAf, const float2* __restrict__ powt) {
  constexpr int KDIM = 512;
  constexpr int NT = KDIM / 32;
  __shared__ u16 lds[24576];             // 48 KB: As[3] | Bs[3]; scratch aliases
  u16* AsB = lds;
  u16* BsB = lds + 12288;
  const int tid = threadIdx.x;
  const int w = tid >> 6, l = tid & 63;
  const int wm = w >> 2, wn = w & 3;

  const int lin = blockIdx.x;
  const int cpx = gridDim.x >> 3;
  const int swz = (lin & 7) * cpx + (lin >> 3);
  const int m0 = swz * 128;

  f32x4 acc[4][2] = {};

  const int lr = l >> 2;
  const int sc = (l & 3) ^ ((l >> 3) & 3);
  const u16* gA = A + (size_t)(m0 + w * 16 + lr) * KDIM + sc * 8;
  const u16* gB = Bt + (size_t)(w * 16 + lr) * KDIM + sc * 8;

  const int fr = l & 15;
  const int kgs = (((l >> 4) ^ (l >> 1)) & 3) * 8;

  auto stage = [&](int buf, int k0) {
    gld16(gA + k0, &AsB[buf * 4096 + w * 512]);
    gld16(gB + k0, &BsB[buf * 4096 + w * 512]);
  };
  auto compute = [&](int buf) {
    short8v af[4], bfr[2];
#pragma unroll
    for (int mi = 0; mi < 4; ++mi)
      af[mi] = *(const short8v*)&AsB[buf * 4096 + (wm * 64 + mi * 16 + fr) * 32 + kgs];
#pragma unroll
    for (int ni = 0; ni < 2; ++ni)
      bfr[ni] = *(const short8v*)&BsB[buf * 4096 + (wn * 32 + ni * 16 + fr) * 32 + kgs];
#pragma unroll
    for (int mi = 0; mi < 4; ++mi)
#pragma unroll
      for (int ni = 0; ni < 2; ++ni)
        acc[mi][ni] = __builtin_amdgcn_mfma_f32_16x16x32_bf16(af[mi], bfr[ni], acc[mi][ni], 0, 0, 0);
  };

  stage(0, 0);
  stage(1, 32);
#pragma unroll
  for (int t = 0; t < NT; ++t) {
    if (t + 1 < NT) { WAITV2; } else { WAITV0; }
    BARRAW;
    if (t + 2 < NT) stage((t + 2) % 3, (t + 2) * 32);
    compute(t % 3);
  }

  const int lg = l >> 4;
  const int rbase = lg * 4;
  // fused chunk carry-sum first (register-only): carr[chunk] = sum_r dA^{63-r} Bu_r
  const int cu = (m0 >> 6) + wm;
#pragma unroll
  for (int ni = 0; ni < 2; ++ni) {
    int gc = wn * 32 + ni * 16 + fr;
    int p = gc & 63;
    float2 dA = dAf[p];
    float sre = 0.f, sim = 0.f;
#pragma unroll
    for (int mi = 0; mi < 4; ++mi) {
      float tr = 0.f, ti = 0.f;
#pragma unroll
      for (int j = 0; j < 4; ++j) {
        float v = acc[mi][ni][j];
        float nr = fmaf(dA.x, tr, fmaf(-dA.y, ti, v));
        float nim = fmaf(dA.x, ti, dA.y * tr);
        tr = nr; ti = nim;
      }
      float2 wg = powt[p * (GCH + 1) + 60 - lg * 4 - 16 * mi];
      sre = fmaf(wg.x, tr, fmaf(-wg.y, ti, sre));
      sim = fmaf(wg.x, ti, fmaf(wg.y, tr, sim));
    }
    sre += __shfl_xor(sre, 16); sim += __shfl_xor(sim, 16);
    sre += __shfl_xor(sre, 32); sim += __shfl_xor(sim, 32);
    if (lg == 0) {
      size_t crow = (size_t)cu * 128;
      if (gc < 64) { carr[crow + p] = sre;  carr[crow + 64 + p] = sim; }
      else         { carr2[crow + p] = -sim; carr2[crow + 64 + p] = sre; }
    }
  }
  // ---- LDS-coalesced Bu epilogue (stride 132) ----
  __syncthreads();
  u16* scr = lds;                        // 128 x 132 u16 = 33,792 B
#pragma unroll
  for (int mi = 0; mi < 4; ++mi) {
#pragma unroll
    for (int ni = 0; ni < 2; ++ni) {
      int lr0 = wm * 64 + mi * 16 + rbase;
      int lc = wn * 32 + ni * 16 + fr;
      unsigned p01 = cvtpk_bf16(acc[mi][ni][0], acc[mi][ni][1]);
      unsigned p23 = cvtpk_bf16(acc[mi][ni][2], acc[mi][ni][3]);
      scr[(lr0 + 0) * 132 + lc] = (u16)p01;
      scr[(lr0 + 1) * 132 + lc] = (u16)(p01 >> 16);
      scr[(lr0 + 2) * 132 + lc] = (u16)p23;
      scr[(lr0 + 3) * 132 + lc] = (u16)(p23 >> 16);
    }
  }
  __syncthreads();
#pragma unroll
  for (int r = 0; r < 4; ++r) {
    int row = (tid >> 4) + r * 32;
    int ch = (tid & 15) * 8;
    uint4 v = *(const uint4*)&scr[row * 132 + ch];
    *(uint4*)&Bu[(size_t)(m0 + row) * 128 + ch] = v;
  }
}

// ---------------- K3b: chunk-carry exclusive prefix scan (pipelined) ----------
__global__ void scan_carry_k(const float* __restrict__ carr, const float* __restrict__ carr2,
                             float* __restrict__ offc, const float2* __restrict__ powt) {
  int b = threadIdx.x >> 6;
  int p = threadIdx.x & 63;
  float2 dAG = powt[p * (GCH + 1) + GCH];   // dA^G
  float rr = 0.f, ri = 0.f;
  float a0[8], b0[8], c0a[8], d0a[8];
  float a1[8], b1[8], c1a[8], d1a[8];

#define LOADB(cb, A_, B_, C_, D_)                                      \
  {                                                                     \
    _Pragma("unroll") for (int j = 0; j < 8; ++j) {                     \
      size_t crow = (size_t)(b * NCH + (cb) + j) * 128;                 \
      A_[j] = carr[crow + p]; B_[j] = carr[crow + 64 + p];              \
      C_[j] = carr2[crow + p]; D_[j] = carr2[crow + 64 + p];            \
    }                                                                   \
  }
#define STEPB(cb, A_, B_, C_, D_)                                      \
  {                                                                     \
    _Pragma("unroll") for (int j = 0; j < 8; ++j) {                     \
      size_t orow = (size_t)(b * NCH + (cb) + j) * 128;                 \
      offc[orow + p] = rr; offc[orow + 64 + p] = ri;                    \
      float er = A_[j] + C_[j], ei = B_[j] + D_[j];                     \
      float nr = fmaf(dAG.x, rr, fmaf(-dAG.y, ri, er));                 \
      float ni = fmaf(dAG.x, ri, fmaf(dAG.y, rr, ei));                  \
      rr = nr; ri = ni;                                                 \
    }                                                                   \
  }

  LOADB(0, a0, b0, c0a, d0a);
  for (int c0 = 0; c0 < NCH; c0 += 16) {
    LOADB(c0 + 8, a1, b1, c1a, d1a);
    STEPB(c0, a0, b0, c0a, d0a);
    if (c0 + 16 < NCH) LOADB(c0 + 16, a0, b0, c0a, d0a);
    STEPB(c0 + 8, a1, b1, c1a, d1a);
  }
#undef LOADB
#undef STEPB
}

// ---------------- K3c: seeded local scan (bf16 Bu in), emits bf16 h ------------
__global__ __launch_bounds__(256) void scan_emit_k(const u16* __restrict__ Bu,
                                                   const float* __restrict__ offc,
                                                   u16* __restrict__ hb,
                                                   const float2* __restrict__ dAf) {
  int unit = blockIdx.x * 4 + (threadIdx.x >> 6);   // b*NCH + c
  int p = threadIdx.x & 63;
  int b = unit >> 8, c = unit & 255;
  float2 dA = dAf[p];
  size_t base = ((size_t)b * LSEQ + (size_t)c * GCH) * 128;
  float hr = offc[(size_t)unit * 128 + p];
  float hi = offc[(size_t)unit * 128 + 64 + p];
  for (int i0 = 0; i0 < GCH; i0 += 8) {
    float br[8], bi[8];
#pragma unroll
    for (int j = 0; j < 8; ++j) {
      br[j] = bf2f(Bu[base + (size_t)(i0 + j) * 128 + p]);
      bi[j] = bf2f(Bu[base + (size_t)(i0 + j) * 128 + 64 + p]);
    }
#pragma unroll
    for (int j = 0; j < 8; ++j) {
      float nr = fmaf(dA.x, hr, fmaf(-dA.y, hi, br[j]));
      float ni = fmaf(dA.x, hi, fmaf(dA.y, hr, bi[j]));
      hr = nr; hi = ni;
      hb[base + (size_t)(i0 + j) * 128 + p] = f2bf(hr);
      hb[base + (size_t)(i0 + j) * 128 + 64 + p] = f2bf(hi);
    }
  }
}

extern "C" void kernel_launch(void* const* d_in, const int* in_sizes, int n_in,
                              void* d_out, int out_size, void* d_ws, size_t ws_size,
                              hipStream_t stream) {
  const float* x      = (const float*)d_in[0];
  const float* W_in   = (const float*)d_in[1];
  const float* W_out  = (const float*)d_in[2];
  const float* A_real = (const float*)d_in[3];
  const float* A_imag = (const float*)d_in[4];
  const float* B_re   = (const float*)d_in[5];
  const float* B_im   = (const float*)d_in[6];
  const float* C_re   = (const float*)d_in[7];
  const float* C_im   = (const float*)d_in[8];
  const float* Dv     = (const float*)d_in[9];
  const float* inv_dt = (const float*)d_in[10];

  // ---- workspace layout (bf16 buffers) ----
  u16* xb    = (u16*)d_ws;                       // N*256
  u16* u_bf  = xb + (size_t)NTOK * 256;          // N*512
  u16* sr_bf = u_bf + (size_t)NTOK * 512;        // N*512 (becomes g after K4a)
  u16* h_bf  = sr_bf + (size_t)NTOK * 512;       // N*128
  u16* WinT  = h_bf + (size_t)NTOK * 128;        // 1024*256
  u16* dBn   = WinT + 1024 * 256;                // 128*512
  u16* Ccb   = dBn + 128 * 512;                  // 512*128
  u16* WoutT = Ccb + 512 * 128;                  // 256*512

  // ---- d_out doubles as scratch (dead before final GEMM writes it) ----
  float* O    = (float*)d_out;
  u16* Bu     = (u16*)O;                  // N*128 u16 = 4194304 float-slots
  float* offc = O + 4194304;              // 1024*128
  float* carr = O + 4325376;              // 1024*128
  float* car2 = O + 4456448;              // 1024*128
  float2* powt = (float2*)(O + 4587520);  // 64*65 float2
  float2* dAf  = (float2*)(O + 4595840);  // 64 float2
  float2* fvec = (float2*)(O + 4595968);  // 64 float2

  setup_scalar_k<<<1, 64, 0, stream>>>(A_real, A_imag, inv_dt, dAf, fvec, powt);
  setup_tables_k<<<256, 256, 0, stream>>>(B_re, B_im, C_re, C_im, W_in, W_out, fvec,
                                          WinT, dBn, Ccb, WoutT);
  cvt_x_k<<<2048, 256, 0, stream>>>(x, xb);

  // K1: [u|res] = silu(x @ W_in)  (512 m-tiles x 8 col-tiles)
  k1_gemm<<<4096, 512, 0, stream>>>(xb, WinT, u_bf, sr_bf);
  // K2: Bu = u @ dB^T (bf16) + fused chunk carry
  k2_bu_carry<<<512, 512, 0, stream>>>(u_bf, dBn, Bu, carr, car2, dAf, powt);
  // K3: carry prefix scan + seeded local scan -> bf16 h
  scan_carry_k<<<1, 256, 0, stream>>>(carr, car2, offc, powt);
  scan_emit_k<<<256, 256, 0, stream>>>(Bu, offc, h_bf, dAf);
  // K4a: g = (Re(h C^T) + D*u) * sres  (512 m-tiles x 2 n-tiles)
  mgemm2<2, 1, 128><<<1024, 1024, 0, stream>>>(h_bf, Ccb, u_bf, sr_bf, Dv);
  // K4b: out = g @ W_out  (512 m-tiles x 1 n-tile)
  mgemm2<3, 0, 512><<<512, 1024, 0, stream>>>(sr_bf, WoutT, O, nullptr, nullptr);
}

// Round 15
// 203.389 us; speedup vs baseline: 1.0318x; 1.0318x over previous
//
#include <hip/hip_runtime.h>
#include <math.h>

#define NTOK 65536
#define LSEQ 16384
#define GCH 64
#define NCH 256   // LSEQ / GCH

typedef __attribute__((ext_vector_type(8))) short short8v;
typedef __attribute__((ext_vector_type(4))) float f32x4;
typedef unsigned short u16;

__device__ __forceinline__ u16 f2bf(float f) {
  unsigned u = __float_as_uint(f);
  return (u16)((u + 0x7FFFu + ((u >> 16) & 1u)) >> 16);
}
__device__ __forceinline__ float bf2f(u16 b) {
  return __uint_as_float(((unsigned)b) << 16);
}
__device__ __forceinline__ unsigned cvtpk_bf16(float lo, float hi) {
  unsigned r;
  asm("v_cvt_pk_bf16_f32 %0, %1, %2" : "=v"(r) : "v"(lo), "v"(hi));
  return r;
}
__device__ __forceinline__ float silu_f(float v) {
  return v * __builtin_amdgcn_rcpf(1.f + __expf(-v));
}
__device__ __forceinline__ void gld16(const u16* g, u16* l) {
  __builtin_amdgcn_global_load_lds((const __attribute__((address_space(1))) void*)g,
                                   (__attribute__((address_space(3))) void*)l, 16, 0, 0);
}

#define WAITV2 asm volatile("s_waitcnt vmcnt(2) lgkmcnt(0)" ::: "memory")
#define WAITV1 asm volatile("s_waitcnt vmcnt(1) lgkmcnt(0)" ::: "memory")
#define WAITV0 asm volatile("s_waitcnt vmcnt(0) lgkmcnt(0)" ::: "memory")
#define BARRAW asm volatile("s_barrier" ::: "memory")

// ---------------- K0a: scalar SSM parameter setup (fp64) ----------------
__global__ void setup_scalar_k(const float* __restrict__ A_real, const float* __restrict__ A_imag,
                               const float* __restrict__ inv_dt,
                               float2* __restrict__ dAf, float2* __restrict__ fvec,
                               float2* __restrict__ powt) {
  int p = threadIdx.x;
  if (p >= 64) return;
  double ar = (double)A_real[p], ai = (double)A_imag[p];
  double dt = log1p(exp((double)inv_dt[p]));   // softplus
  double zr = 0.5 * dt * ar, zi = 0.5 * dt * ai;
  double d1r = 1.0 - zr;
  double den = d1r * d1r + zi * zi;
  double blr = d1r / den, bli = zi / den;      // BL = 1/(1-z)
  double nr = 1.0 + zr, ni = zi;               // 1+z
  double dar = blr * nr - bli * ni;            // dA
  double dai = blr * ni + bli * nr;
  dAf[p] = make_float2((float)dar, (float)dai);
  fvec[p] = make_float2((float)(blr * dt), (float)(bli * dt));   // f = BL*dt
  double cr = 1.0, ci = 0.0;
  for (int k = 0; k <= GCH; ++k) {
    powt[p * (GCH + 1) + k] = make_float2((float)cr, (float)ci); // dA^k
    double t = cr * dar - ci * dai;
    ci = cr * dai + ci * dar;
    cr = t;
  }
}

// ---------------- K0b: build bf16 B^T-layout weight tables ----------------
__global__ void setup_tables_k(const float* __restrict__ B_re, const float* __restrict__ B_im,
                               const float* __restrict__ C_re, const float* __restrict__ C_im,
                               const float* __restrict__ W_in, const float* __restrict__ W_out,
                               const float2* __restrict__ fvec,
                               u16* __restrict__ WinT, u16* __restrict__ dBn,
                               u16* __restrict__ Ccb, u16* __restrict__ WoutT) {
  int idx = blockIdx.x * blockDim.x + threadIdx.x;
  int stride = gridDim.x * blockDim.x;
  // WinT [1024][256]
  for (int i = idx; i < 1024 * 256; i += stride) {
    int n = i >> 8, k = i & 255;
    WinT[i] = f2bf(W_in[k * 1024 + n]);
  }
  // dBn [128][512]  (rows 0-63 Re(dB), 64-127 Im(dB))
  for (int i = idx; i < 128 * 512; i += stride) {
    int p = i >> 9, d = i & 511;
    float2 f = fvec[p & 63];
    float br = B_re[(p & 63) * 512 + d], bi = B_im[(p & 63) * 512 + d];
    float v = (p < 64) ? (f.x * br - f.y * bi) : (f.x * bi + f.y * br);
    dBn[i] = f2bf(v);
  }
  // Ccb [512][128]  (cols 0-63: C_re, 64-127: -C_im)
  for (int i = idx; i < 512 * 128; i += stride) {
    int d = i >> 7, k = i & 127;
    float v = (k < 64) ? C_re[d * 64 + k] : -C_im[d * 64 + (k - 64)];
    Ccb[i] = f2bf(v);
  }
  // WoutT [256][512]
  for (int i = idx; i < 256 * 512; i += stride) {
    int n = i >> 9, k = i & 511;
    WoutT[i] = f2bf(W_out[k * 256 + n]);
  }
}

// ---------------- x -> bf16 ----------------
__global__ __launch_bounds__(256) void cvt_x_k(const float* __restrict__ x, u16* __restrict__ xb) {
  size_t i = ((size_t)blockIdx.x * blockDim.x + threadIdx.x) * 4;
  size_t stride = (size_t)gridDim.x * blockDim.x * 4;
  const size_t total = (size_t)NTOK * 256;
  for (; i < total; i += stride) {
    float4 v = *(const float4*)(x + i);
    ushort4 o;
    o.x = f2bf(v.x); o.y = f2bf(v.y); o.z = f2bf(v.z); o.w = f2bf(v.w);
    *(ushort4*)(xb + i) = o;
  }
}

// ---------------- K1: [u|res] = silu(xb @ WinT) — rotated-chunk epilogue -------
// 8 waves (2x4), 128x128 tile, BK=32, NT=8, gld_lds both operands, 3 LDS bufs,
// depth-2 counted vmcnt(2). Epilogue scratch [128][128] u16 (no pad): physical
// 16B-chunk = (logical + 2*((row>>2)&3)) & 15 -> writes hit disjoint chunk
// pairs per lane-group (2-way banks = free, m136), reads stay 16B-aligned
// single b128 (R14's padded strides broke alignment -> split reads, +7us).
__global__ __launch_bounds__(512) void k1_gemm(
    const u16* __restrict__ A, const u16* __restrict__ Bt,
    u16* __restrict__ u_bf, u16* __restrict__ sr_bf) {
  constexpr int KDIM = 256, NT = 8;
  __shared__ u16 lds[24576];             // 48 KB: As[3] | Bs[3]; scratch aliases
  u16* AsB = lds;
  u16* BsB = lds + 12288;
  const int tid = threadIdx.x;
  const int w = tid >> 6, l = tid & 63;
  const int wm = w >> 2, wn = w & 3;

  const int lin = blockIdx.x;
  const int cpx = gridDim.x >> 3;
  const int swz = (lin & 7) * cpx + (lin >> 3);
  const int n0 = (swz & 7) * 128;
  const int m0 = (swz >> 3) * 128;

  f32x4 acc[4][2] = {};

  const int lr = l >> 2;
  const int sc = (l & 3) ^ ((l >> 3) & 3);
  const u16* gA = A + (size_t)(m0 + w * 16 + lr) * KDIM + sc * 8;
  const u16* gB = Bt + (size_t)(n0 + w * 16 + lr) * KDIM + sc * 8;

  const int fr = l & 15;
  const int kgs = (((l >> 4) ^ (l >> 1)) & 3) * 8;

  auto stage = [&](int buf, int k0) {
    gld16(gA + k0, &AsB[buf * 4096 + w * 512]);
    gld16(gB + k0, &BsB[buf * 4096 + w * 512]);
  };
  auto compute = [&](int buf) {
    short8v af[4], bfr[2];
#pragma unroll
    for (int mi = 0; mi < 4; ++mi)
      af[mi] = *(const short8v*)&AsB[buf * 4096 + (wm * 64 + mi * 16 + fr) * 32 + kgs];
#pragma unroll
    for (int ni = 0; ni < 2; ++ni)
      bfr[ni] = *(const short8v*)&BsB[buf * 4096 + (wn * 32 + ni * 16 + fr) * 32 + kgs];
#pragma unroll
    for (int mi = 0; mi < 4; ++mi)
#pragma unroll
      for (int ni = 0; ni < 2; ++ni)
        acc[mi][ni] = __builtin_amdgcn_mfma_f32_16x16x32_bf16(af[mi], bfr[ni], acc[mi][ni], 0, 0, 0);
  };

  stage(0, 0);
  stage(1, 32);
#pragma unroll
  for (int t = 0; t < NT; ++t) {
    if (t + 1 < NT) { WAITV2; } else { WAITV0; }
    BARRAW;
    if (t + 2 < NT) stage((t + 2) % 3, (t + 2) * 32);
    compute(t % 3);
  }

  // ---- rotated-chunk LDS epilogue ----
  __syncthreads();
  u16* scr = lds;                        // 128 x 128 u16 = 32 KB
  const int g = l >> 4;                  // (row>>2)&3 for all rows this thread writes
  const int rbase = g * 4;
#pragma unroll
  for (int mi = 0; mi < 4; ++mi) {
#pragma unroll
    for (int ni = 0; ni < 2; ++ni) {
      int lr0 = wm * 64 + mi * 16 + rbase;
      int lc = wn * 32 + ni * 16 + fr;
      int col = (((lc >> 3) + 2 * g) & 15) * 8 + (lc & 7);
      float s0 = silu_f(acc[mi][ni][0]);
      float s1 = silu_f(acc[mi][ni][1]);
      float s2 = silu_f(acc[mi][ni][2]);
      float s3 = silu_f(acc[mi][ni][3]);
      unsigned p01 = cvtpk_bf16(s0, s1);
      unsigned p23 = cvtpk_bf16(s2, s3);
      scr[(lr0 + 0) * 128 + col] = (u16)p01;
      scr[(lr0 + 1) * 128 + col] = (u16)(p01 >> 16);
      scr[(lr0 + 2) * 128 + col] = (u16)p23;
      scr[(lr0 + 3) * 128 + col] = (u16)(p23 >> 16);
    }
  }
  __syncthreads();
  u16* Cw = (n0 < 512) ? u_bf : sr_bf;
  const int cb = (n0 < 512) ? n0 : (n0 - 512);
#pragma unroll
  for (int r = 0; r < 4; ++r) {
    int row = (tid >> 4) + r * 32;
    int c = tid & 15;
    int pc = (c + 2 * ((row >> 2) & 3)) & 15;
    uint4 v = *(const uint4*)&scr[row * 128 + pc * 8];
    *(uint4*)&Cw[(size_t)(m0 + row) * 512 + cb + c * 8] = v;
  }
}

// ------------- 16-wave MFMA GEMM: 128x256 tile, BK=32, 1024 threads -------------
// Waves 0-7 stage A (gld_lds), waves 8-15 stage B (2 gld_lds). 3 bufs, depth-2,
// per-wave counted vmcnt (A:1, B:2).
// MODE 2: g tile via rotated-chunk bf16 epilogue [128][256]
// MODE 3: fp32 out via 2-pass rotated-chunk epilogue [64][256]
template<int MODE, int LOG_NBX, int KDIM>
__global__ __launch_bounds__(1024) void mgemm2(
    const u16* __restrict__ Ain, const u16* __restrict__ Bt,
    void* __restrict__ C0, void* __restrict__ C1,
    const float* __restrict__ Dvec) {
  constexpr int NT = KDIM / 32;
  __shared__ u16 lds[36864];             // 72 KB: As[3] | Bs[3]; scratch aliases
  u16* AsB = lds;
  u16* BsB = lds + 12288;
  const int tid = threadIdx.x;
  const int w = tid >> 6, l = tid & 63;
  const int wm = w >> 3, wn = w & 7;
  const bool isA = (w < 8);

  const int lin = blockIdx.x;
  const int cpx = gridDim.x >> 3;
  const int swz = (lin & 7) * cpx + (lin >> 3);
  const int n0 = (swz & ((1 << LOG_NBX) - 1)) * 256;
  const int m0 = (swz >> LOG_NBX) * 128;

  f32x4 acc[4][2] = {};

  const int fr = l & 15;
  const int kgs = (((l >> 4) ^ (l >> 1)) & 3) * 8;
  const int sr = l >> 2;
  const int scs = (l & 3) ^ ((l >> 3) & 3);

  const u16* gA = nullptr;
  const u16* gB = nullptr;
  if (isA) gA = Ain + (size_t)(m0 + w * 16 + sr) * KDIM + scs * 8;
  else     gB = Bt + (size_t)(n0 + (w - 8) * 16 + sr) * KDIM + scs * 8;

  auto stage = [&](int buf, int k0) {
    if (isA) {
      gld16(gA + k0, &AsB[buf * 4096 + w * 512]);
    } else {
      gld16(gB + k0, &BsB[buf * 8192 + (w - 8) * 512]);
      gld16(gB + k0 + (size_t)128 * KDIM, &BsB[buf * 8192 + (w - 8) * 512 + 4096]);
    }
  };
  auto compute = [&](int buf) {
    short8v af[4], bfr[2];
#pragma unroll
    for (int mi = 0; mi < 4; ++mi)
      af[mi] = *(const short8v*)&AsB[buf * 4096 + (wm * 64 + mi * 16 + fr) * 32 + kgs];
#pragma unroll
    for (int ni = 0; ni < 2; ++ni)
      bfr[ni] = *(const short8v*)&BsB[buf * 8192 + (wn * 32 + ni * 16 + fr) * 32 + kgs];
#pragma unroll
    for (int mi = 0; mi < 4; ++mi)
#pragma unroll
      for (int ni = 0; ni < 2; ++ni)
        acc[mi][ni] = __builtin_amdgcn_mfma_f32_16x16x32_bf16(af[mi], bfr[ni], acc[mi][ni], 0, 0, 0);
  };

  stage(0, 0);
  stage(1, 32);
#pragma unroll
  for (int t = 0; t < NT; ++t) {
    if (t + 1 < NT) { if (isA) { WAITV1; } else { WAITV2; } } else { WAITV0; }
    BARRAW;
    if (t + 2 < NT) stage((t + 2) % 3, (t + 2) * 32);
    compute(t % 3);
  }

  const int g = l >> 4;
  const int rbase = g * 4;
  if (MODE == 2) {
    // ---- rotated-chunk bf16 epilogue: [128][256] u16 = 64 KB ----
    __syncthreads();
    u16* scr = lds;
#pragma unroll
    for (int mi = 0; mi < 4; ++mi) {
#pragma unroll
      for (int ni = 0; ni < 2; ++ni) {
        int lr0 = wm * 64 + mi * 16 + rbase;
        int lc = wn * 32 + ni * 16 + fr;
        int col = (((lc >> 3) + 2 * g) & 31) * 8 + (lc & 7);
        int gr0 = m0 + lr0;
        int gc = n0 + lc;
        float gg[4];
#pragma unroll
        for (int j = 0; j < 4; ++j) {
          size_t r = (size_t)(gr0 + j);
          float uu = bf2f(((const u16*)C0)[r * 512 + gc]);
          float sr2 = bf2f(((const u16*)C1)[r * 512 + gc]);
          gg[j] = (acc[mi][ni][j] + Dvec[gc] * uu) * sr2;
        }
        unsigned p01 = cvtpk_bf16(gg[0], gg[1]);
        unsigned p23 = cvtpk_bf16(gg[2], gg[3]);
        scr[(lr0 + 0) * 256 + col] = (u16)p01;
        scr[(lr0 + 1) * 256 + col] = (u16)(p01 >> 16);
        scr[(lr0 + 2) * 256 + col] = (u16)p23;
        scr[(lr0 + 3) * 256 + col] = (u16)(p23 >> 16);
      }
    }
    __syncthreads();
#pragma unroll
    for (int r = 0; r < 4; ++r) {
      int row = (tid >> 5) + r * 32;
      int c = tid & 31;
      int pc = (c + 2 * ((row >> 2) & 3)) & 31;
      uint4 v = *(const uint4*)&scr[row * 256 + pc * 8];
      *(uint4*)&((u16*)C1)[(size_t)(m0 + row) * 512 + n0 + c * 8] = v;
    }
  } else {
    // ---- 2-pass rotated-chunk fp32 epilogue: [64][256] f32 = 64 KB ----
    float* scrf = (float*)lds;
#pragma unroll
    for (int pass = 0; pass < 2; ++pass) {
      __syncthreads();
      if (wm == pass) {
#pragma unroll
        for (int mi = 0; mi < 4; ++mi) {
#pragma unroll
          for (int ni = 0; ni < 2; ++ni) {
            int lr0 = mi * 16 + rbase;   // row within 64-row half
            int lc = wn * 32 + ni * 16 + fr;
            int col = (((lc >> 2) + 2 * g) & 63) * 4 + (lc & 3);
#pragma unroll
            for (int j = 0; j < 4; ++j)
              scrf[(lr0 + j) * 256 + col] = acc[mi][ni][j];
          }
        }
      }
      __syncthreads();
#pragma unroll
      for (int r = 0; r < 4; ++r) {
        int row = tid >> 4;              // 0..63
        int ch = (tid & 15) * 4 + r * 64;
        int pc = ((ch >> 2) + 2 * ((row >> 2) & 3)) & 63;
        float4 v = *(const float4*)&scrf[row * 256 + pc * 4];
        *(float4*)&((float*)C0)[(size_t)(m0 + pass * 64 + row) * 256 + n0 + ch] = v;
      }
    }
  }
}

// ---------------- K2: Bu(bf16) = u @ dB^T + fused chunk carry-sum ----------
// Bu written via rotated-chunk epilogue [128][128]; carry sums fp32.
__global__ __launch_bounds__(512) void k2_bu_carry(
    const u16* __restrict__ A, const u16* __restrict__ Bt,
    u16* __restrict__ Bu, float* __restrict__ carr, float* __restrict__ carr2,
    const float2* __restrict__ dAf, const float2* __restrict__ powt) {
  constexpr int KDIM = 512;
  constexpr int NT = KDIM / 32;
  __shared__ u16 lds[24576];             // 48 KB
  u16* AsB = lds;
  u16* BsB = lds + 12288;
  const int tid = threadIdx.x;
  const int w = tid >> 6, l = tid & 63;
  const int wm = w >> 2, wn = w & 3;

  const int lin = blockIdx.x;
  const int cpx = gridDim.x >> 3;
  const int swz = (lin & 7) * cpx + (lin >> 3);
  const int m0 = swz * 128;

  f32x4 acc[4][2] = {};

  const int lr = l >> 2;
  const int sc = (l & 3) ^ ((l >> 3) & 3);
  const u16* gA = A + (size_t)(m0 + w * 16 + lr) * KDIM + sc * 8;
  const u16* gB = Bt + (size_t)(w * 16 + lr) * KDIM + sc * 8;

  const int fr = l & 15;
  const int kgs = (((l >> 4) ^ (l >> 1)) & 3) * 8;

  auto stage = [&](int buf, int k0) {
    gld16(gA + k0, &AsB[buf * 4096 + w * 512]);
    gld16(gB + k0, &BsB[buf * 4096 + w * 512]);
  };
  auto compute = [&](int buf) {
    short8v af[4], bfr[2];
#pragma unroll
    for (int mi = 0; mi < 4; ++mi)
      af[mi] = *(const short8v*)&AsB[buf * 4096 + (wm * 64 + mi * 16 + fr) * 32 + kgs];
#pragma unroll
    for (int ni = 0; ni < 2; ++ni)
      bfr[ni] = *(const short8v*)&BsB[buf * 4096 + (wn * 32 + ni * 16 + fr) * 32 + kgs];
#pragma unroll
    for (int mi = 0; mi < 4; ++mi)
#pragma unroll
      for (int ni = 0; ni < 2; ++ni)
        acc[mi][ni] = __builtin_amdgcn_mfma_f32_16x16x32_bf16(af[mi], bfr[ni], acc[mi][ni], 0, 0, 0);
  };

  stage(0, 0);
  stage(1, 32);
#pragma unroll
  for (int t = 0; t < NT; ++t) {
    if (t + 1 < NT) { WAITV2; } else { WAITV0; }
    BARRAW;
    if (t + 2 < NT) stage((t + 2) % 3, (t + 2) * 32);
    compute(t % 3);
  }

  const int g = l >> 4;
  const int rbase = g * 4;
  // fused chunk carry-sum (register-only): carr[chunk] = sum_r dA^{63-r} Bu_r
  const int cu = (m0 >> 6) + wm;
#pragma unroll
  for (int ni = 0; ni < 2; ++ni) {
    int gc = wn * 32 + ni * 16 + fr;
    int p = gc & 63;
    float2 dA = dAf[p];
    float sre = 0.f, sim = 0.f;
#pragma unroll
    for (int mi = 0; mi < 4; ++mi) {
      float tr = 0.f, ti = 0.f;
#pragma unroll
      for (int j = 0; j < 4; ++j) {
        float v = acc[mi][ni][j];
        float nr = fmaf(dA.x, tr, fmaf(-dA.y, ti, v));
        float nim = fmaf(dA.x, ti, dA.y * tr);
        tr = nr; ti = nim;
      }
      float2 wg = powt[p * (GCH + 1) + 60 - g * 4 - 16 * mi];
      sre = fmaf(wg.x, tr, fmaf(-wg.y, ti, sre));
      sim = fmaf(wg.x, ti, fmaf(wg.y, tr, sim));
    }
    sre += __shfl_xor(sre, 16); sim += __shfl_xor(sim, 16);
    sre += __shfl_xor(sre, 32); sim += __shfl_xor(sim, 32);
    if (g == 0) {
      size_t crow = (size_t)cu * 128;
      if (gc < 64) { carr[crow + p] = sre;  carr[crow + 64 + p] = sim; }
      else         { carr2[crow + p] = -sim; carr2[crow + 64 + p] = sre; }
    }
  }
  // ---- rotated-chunk Bu epilogue [128][128] ----
  __syncthreads();
  u16* scr = lds;
#pragma unroll
  for (int mi = 0; mi < 4; ++mi) {
#pragma unroll
    for (int ni = 0; ni < 2; ++ni) {
      int lr0 = wm * 64 + mi * 16 + rbase;
      int lc = wn * 32 + ni * 16 + fr;
      int col = (((lc >> 3) + 2 * g) & 15) * 8 + (lc & 7);
      unsigned p01 = cvtpk_bf16(acc[mi][ni][0], acc[mi][ni][1]);
      unsigned p23 = cvtpk_bf16(acc[mi][ni][2], acc[mi][ni][3]);
      scr[(lr0 + 0) * 128 + col] = (u16)p01;
      scr[(lr0 + 1) * 128 + col] = (u16)(p01 >> 16);
      scr[(lr0 + 2) * 128 + col] = (u16)p23;
      scr[(lr0 + 3) * 128 + col] = (u16)(p23 >> 16);
    }
  }
  __syncthreads();
#pragma unroll
  for (int r = 0; r < 4; ++r) {
    int row = (tid >> 4) + r * 32;
    int c = tid & 15;
    int pc = (c + 2 * ((row >> 2) & 3)) & 15;
    uint4 v = *(const uint4*)&scr[row * 128 + pc * 8];
    *(uint4*)&Bu[(size_t)(m0 + row) * 128 + c * 8] = v;
  }
}

// ---------------- K3b: chunk-carry exclusive prefix scan (pipelined) ----------
__global__ void scan_carry_k(const float* __restrict__ carr, const float* __restrict__ carr2,
                             float* __restrict__ offc, const float2* __restrict__ powt) {
  int b = threadIdx.x >> 6;
  int p = threadIdx.x & 63;
  float2 dAG = powt[p * (GCH + 1) + GCH];   // dA^G
  float rr = 0.f, ri = 0.f;
  float a0[8], b0[8], c0a[8], d0a[8];
  float a1[8], b1[8], c1a[8], d1a[8];

#define LOADB(cb, A_, B_, C_, D_)                                      \
  {                                                                     \
    _Pragma("unroll") for (int j = 0; j < 8; ++j) {                     \
      size_t crow = (size_t)(b * NCH + (cb) + j) * 128;                 \
      A_[j] = carr[crow + p]; B_[j] = carr[crow + 64 + p];              \
      C_[j] = carr2[crow + p]; D_[j] = carr2[crow + 64 + p];            \
    }                                                                   \
  }
#define STEPB(cb, A_, B_, C_, D_)                                      \
  {                                                                     \
    _Pragma("unroll") for (int j = 0; j < 8; ++j) {                     \
      size_t orow = (size_t)(b * NCH + (cb) + j) * 128;                 \
      offc[orow + p] = rr; offc[orow + 64 + p] = ri;                    \
      float er = A_[j] + C_[j], ei = B_[j] + D_[j];                     \
      float nr = fmaf(dAG.x, rr, fmaf(-dAG.y, ri, er));                 \
      float ni = fmaf(dAG.x, ri, fmaf(dAG.y, rr, ei));                  \
      rr = nr; ri = ni;                                                 \
    }                                                                   \
  }

  LOADB(0, a0, b0, c0a, d0a);
  for (int c0 = 0; c0 < NCH; c0 += 16) {
    LOADB(c0 + 8, a1, b1, c1a, d1a);
    STEPB(c0, a0, b0, c0a, d0a);
    if (c0 + 16 < NCH) LOADB(c0 + 16, a0, b0, c0a, d0a);
    STEPB(c0 + 8, a1, b1, c1a, d1a);
  }
#undef LOADB
#undef STEPB
}

// ---------------- K3c: seeded local scan (bf16 Bu in), emits bf16 h ------------
__global__ __launch_bounds__(256) void scan_emit_k(const u16* __restrict__ Bu,
                                                   const float* __restrict__ offc,
                                                   u16* __restrict__ hb,
                                                   const float2* __restrict__ dAf) {
  int unit = blockIdx.x * 4 + (threadIdx.x >> 6);   // b*NCH + c
  int p = threadIdx.x & 63;
  int b = unit >> 8, c = unit & 255;
  float2 dA = dAf[p];
  size_t base = ((size_t)b * LSEQ + (size_t)c * GCH) * 128;
  float hr = offc[(size_t)unit * 128 + p];
  float hi = offc[(size_t)unit * 128 + 64 + p];
  for (int i0 = 0; i0 < GCH; i0 += 8) {
    float br[8], bi[8];
#pragma unroll
    for (int j = 0; j < 8; ++j) {
      br[j] = bf2f(Bu[base + (size_t)(i0 + j) * 128 + p]);
      bi[j] = bf2f(Bu[base + (size_t)(i0 + j) * 128 + 64 + p]);
    }
#pragma unroll
    for (int j = 0; j < 8; ++j) {
      float nr = fmaf(dA.x, hr, fmaf(-dA.y, hi, br[j]));
      float ni = fmaf(dA.x, hi, fmaf(dA.y, hr, bi[j]));
      hr = nr; hi = ni;
      hb[base + (size_t)(i0 + j) * 128 + p] = f2bf(hr);
      hb[base + (size_t)(i0 + j) * 128 + 64 + p] = f2bf(hi);
    }
  }
}

extern "C" void kernel_launch(void* const* d_in, const int* in_sizes, int n_in,
                              void* d_out, int out_size, void* d_ws, size_t ws_size,
                              hipStream_t stream) {
  const float* x      = (const float*)d_in[0];
  const float* W_in   = (const float*)d_in[1];
  const float* W_out  = (const float*)d_in[2];
  const float* A_real = (const float*)d_in[3];
  const float* A_imag = (const float*)d_in[4];
  const float* B_re   = (const float*)d_in[5];
  const float* B_im   = (const float*)d_in[6];
  const float* C_re   = (const float*)d_in[7];
  const float* C_im   = (const float*)d_in[8];
  const float* Dv     = (const float*)d_in[9];
  const float* inv_dt = (const float*)d_in[10];

  // ---- workspace layout (bf16 buffers) ----
  u16* xb    = (u16*)d_ws;                       // N*256
  u16* u_bf  = xb + (size_t)NTOK * 256;          // N*512
  u16* sr_bf = u_bf + (size_t)NTOK * 512;        // N*512 (becomes g after K4a)
  u16* h_bf  = sr_bf + (size_t)NTOK * 512;       // N*128
  u16* WinT  = h_bf + (size_t)NTOK * 128;        // 1024*256
  u16* dBn   = WinT + 1024 * 256;                // 128*512
  u16* Ccb   = dBn + 128 * 512;                  // 512*128
  u16* WoutT = Ccb + 512 * 128;                  // 256*512

  // ---- d_out doubles as scratch (dead before final GEMM writes it) ----
  float* O    = (float*)d_out;
  u16* Bu     = (u16*)O;                  // N*128 u16 = 4194304 float-slots
  float* offc = O + 4194304;              // 1024*128
  float* carr = O + 4325376;              // 1024*128
  float* car2 = O + 4456448;              // 1024*128
  float2* powt = (float2*)(O + 4587520);  // 64*65 float2
  float2* dAf  = (float2*)(O + 4595840);  // 64 float2
  float2* fvec = (float2*)(O + 4595968);  // 64 float2

  setup_scalar_k<<<1, 64, 0, stream>>>(A_real, A_imag, inv_dt, dAf, fvec, powt);
  setup_tables_k<<<256, 256, 0, stream>>>(B_re, B_im, C_re, C_im, W_in, W_out, fvec,
                                          WinT, dBn, Ccb, WoutT);
  cvt_x_k<<<2048, 256, 0, stream>>>(x, xb);

  // K1: [u|res] = silu(x @ W_in)  (512 m-tiles x 8 col-tiles)
  k1_gemm<<<4096, 512, 0, stream>>>(xb, WinT, u_bf, sr_bf);
  // K2: Bu = u @ dB^T (bf16) + fused chunk carry
  k2_bu_carry<<<512, 512, 0, stream>>>(u_bf, dBn, Bu, carr, car2, dAf, powt);
  // K3: carry prefix scan + seeded local scan -> bf16 h
  scan_carry_k<<<1, 256, 0, stream>>>(carr, car2, offc, powt);
  scan_emit_k<<<256, 256, 0, stream>>>(Bu, offc, h_bf, dAf);
  // K4a: g = (Re(h C^T) + D*u) * sres  (512 m-tiles x 2 n-tiles)
  mgemm2<2, 1, 128><<<1024, 1024, 0, stream>>>(h_bf, Ccb, u_bf, sr_bf, Dv);
  // K4b: out = g @ W_out  (512 m-tiles x 1 n-tile)
  mgemm2<3, 0, 512><<<512, 1024, 0, stream>>>(sr_bf, WoutT, O, nullptr, nullptr);
}

// Round 16
// 200.104 us; speedup vs baseline: 1.0487x; 1.0164x over previous
//
#include <hip/hip_runtime.h>
#include <math.h>

#define NTOK 65536
#define LSEQ 16384
#define GCH 64
#define NCH 256   // LSEQ / GCH

typedef __attribute__((ext_vector_type(8))) short short8v;
typedef __attribute__((ext_vector_type(4))) float f32x4;
typedef unsigned short u16;

__device__ __forceinline__ u16 f2bf(float f) {
  unsigned u = __float_as_uint(f);
  return (u16)((u + 0x7FFFu + ((u >> 16) & 1u)) >> 16);
}
__device__ __forceinline__ float bf2f(u16 b) {
  return __uint_as_float(((unsigned)b) << 16);
}
__device__ __forceinline__ unsigned cvtpk_bf16(float lo, float hi) {
  unsigned r;
  asm("v_cvt_pk_bf16_f32 %0, %1, %2" : "=v"(r) : "v"(lo), "v"(hi));
  return r;
}
__device__ __forceinline__ float silu_f(float v) {
  return v * __builtin_amdgcn_rcpf(1.f + __expf(-v));
}
__device__ __forceinline__ void gld16(const u16* g, u16* l) {
  __builtin_amdgcn_global_load_lds((const __attribute__((address_space(1))) void*)g,
                                   (__attribute__((address_space(3))) void*)l, 16, 0, 0);
}

#define WAITV2 asm volatile("s_waitcnt vmcnt(2) lgkmcnt(0)" ::: "memory")
#define WAITV1 asm volatile("s_waitcnt vmcnt(1) lgkmcnt(0)" ::: "memory")
#define WAITV0 asm volatile("s_waitcnt vmcnt(0) lgkmcnt(0)" ::: "memory")
#define BARRAW asm volatile("s_barrier" ::: "memory")

// ---------------- K0a: scalar SSM parameter setup (fp64) ----------------
__global__ void setup_scalar_k(const float* __restrict__ A_real, const float* __restrict__ A_imag,
                               const float* __restrict__ inv_dt,
                               float2* __restrict__ dAf, float2* __restrict__ fvec,
                               float2* __restrict__ powt) {
  int p = threadIdx.x;
  if (p >= 64) return;
  double ar = (double)A_real[p], ai = (double)A_imag[p];
  double dt = log1p(exp((double)inv_dt[p]));   // softplus
  double zr = 0.5 * dt * ar, zi = 0.5 * dt * ai;
  double d1r = 1.0 - zr;
  double den = d1r * d1r + zi * zi;
  double blr = d1r / den, bli = zi / den;      // BL = 1/(1-z)
  double nr = 1.0 + zr, ni = zi;               // 1+z
  double dar = blr * nr - bli * ni;            // dA
  double dai = blr * ni + bli * nr;
  dAf[p] = make_float2((float)dar, (float)dai);
  fvec[p] = make_float2((float)(blr * dt), (float)(bli * dt));   // f = BL*dt
  double cr = 1.0, ci = 0.0;
  for (int k = 0; k <= GCH; ++k) {
    powt[p * (GCH + 1) + k] = make_float2((float)cr, (float)ci); // dA^k
    double t = cr * dar - ci * dai;
    ci = cr * dai + ci * dar;
    cr = t;
  }
}

// ---------------- K0b: build bf16 B^T-layout weight tables ----------------
__global__ void setup_tables_k(const float* __restrict__ B_re, const float* __restrict__ B_im,
                               const float* __restrict__ C_re, const float* __restrict__ C_im,
                               const float* __restrict__ W_in, const float* __restrict__ W_out,
                               const float2* __restrict__ fvec,
                               u16* __restrict__ WinT, u16* __restrict__ dBn,
                               u16* __restrict__ Ccb, u16* __restrict__ WoutT) {
  int idx = blockIdx.x * blockDim.x + threadIdx.x;
  int stride = gridDim.x * blockDim.x;
  // WinT [1024][256]
  for (int i = idx; i < 1024 * 256; i += stride) {
    int n = i >> 8, k = i & 255;
    WinT[i] = f2bf(W_in[k * 1024 + n]);
  }
  // dBn [128][512]  (rows 0-63 Re(dB), 64-127 Im(dB))
  for (int i = idx; i < 128 * 512; i += stride) {
    int p = i >> 9, d = i & 511;
    float2 f = fvec[p & 63];
    float br = B_re[(p & 63) * 512 + d], bi = B_im[(p & 63) * 512 + d];
    float v = (p < 64) ? (f.x * br - f.y * bi) : (f.x * bi + f.y * br);
    dBn[i] = f2bf(v);
  }
  // Ccb [512][128]  (cols 0-63: C_re, 64-127: -C_im)
  for (int i = idx; i < 512 * 128; i += stride) {
    int d = i >> 7, k = i & 127;
    float v = (k < 64) ? C_re[d * 64 + k] : -C_im[d * 64 + (k - 64)];
    Ccb[i] = f2bf(v);
  }
  // WoutT [256][512]
  for (int i = idx; i < 256 * 512; i += stride) {
    int n = i >> 9, k = i & 511;
    WoutT[i] = f2bf(W_out[k * 256 + n]);
  }
}

// ---------------- x -> bf16 ----------------
__global__ __launch_bounds__(256) void cvt_x_k(const float* __restrict__ x, u16* __restrict__ xb) {
  size_t i = ((size_t)blockIdx.x * blockDim.x + threadIdx.x) * 4;
  size_t stride = (size_t)gridDim.x * blockDim.x * 4;
  const size_t total = (size_t)NTOK * 256;
  for (; i < total; i += stride) {
    float4 v = *(const float4*)(x + i);
    ushort4 o;
    o.x = f2bf(v.x); o.y = f2bf(v.y); o.z = f2bf(v.z); o.w = f2bf(v.w);
    *(ushort4*)(xb + i) = o;
  }
}

// ---------------- K1: [u|res] = silu(xb @ WinT) — rotated-chunk epilogue -------
// 8 waves (2x4), 128x128 tile, BK=32, NT=8, gld_lds both operands, 3 LDS bufs,
// depth-2 counted vmcnt(2). Epilogue scratch [128][128] u16 (no pad): physical
// 16B-chunk = (logical + 2*((row>>2)&3)) & 15 -> conflict-free writes, aligned
// b128 reads. Measured best K1: 52.7us (R15).
__global__ __launch_bounds__(512) void k1_gemm(
    const u16* __restrict__ A, const u16* __restrict__ Bt,
    u16* __restrict__ u_bf, u16* __restrict__ sr_bf) {
  constexpr int KDIM = 256, NT = 8;
  __shared__ u16 lds[24576];             // 48 KB: As[3] | Bs[3]; scratch aliases
  u16* AsB = lds;
  u16* BsB = lds + 12288;
  const int tid = threadIdx.x;
  const int w = tid >> 6, l = tid & 63;
  const int wm = w >> 2, wn = w & 3;

  const int lin = blockIdx.x;
  const int cpx = gridDim.x >> 3;
  const int swz = (lin & 7) * cpx + (lin >> 3);
  const int n0 = (swz & 7) * 128;
  const int m0 = (swz >> 3) * 128;

  f32x4 acc[4][2] = {};

  const int lr = l >> 2;
  const int sc = (l & 3) ^ ((l >> 3) & 3);
  const u16* gA = A + (size_t)(m0 + w * 16 + lr) * KDIM + sc * 8;
  const u16* gB = Bt + (size_t)(n0 + w * 16 + lr) * KDIM + sc * 8;

  const int fr = l & 15;
  const int kgs = (((l >> 4) ^ (l >> 1)) & 3) * 8;

  auto stage = [&](int buf, int k0) {
    gld16(gA + k0, &AsB[buf * 4096 + w * 512]);
    gld16(gB + k0, &BsB[buf * 4096 + w * 512]);
  };
  auto compute = [&](int buf) {
    short8v af[4], bfr[2];
#pragma unroll
    for (int mi = 0; mi < 4; ++mi)
      af[mi] = *(const short8v*)&AsB[buf * 4096 + (wm * 64 + mi * 16 + fr) * 32 + kgs];
#pragma unroll
    for (int ni = 0; ni < 2; ++ni)
      bfr[ni] = *(const short8v*)&BsB[buf * 4096 + (wn * 32 + ni * 16 + fr) * 32 + kgs];
#pragma unroll
    for (int mi = 0; mi < 4; ++mi)
#pragma unroll
      for (int ni = 0; ni < 2; ++ni)
        acc[mi][ni] = __builtin_amdgcn_mfma_f32_16x16x32_bf16(af[mi], bfr[ni], acc[mi][ni], 0, 0, 0);
  };

  stage(0, 0);
  stage(1, 32);
#pragma unroll
  for (int t = 0; t < NT; ++t) {
    if (t + 1 < NT) { WAITV2; } else { WAITV0; }
    BARRAW;
    if (t + 2 < NT) stage((t + 2) % 3, (t + 2) * 32);
    compute(t % 3);
  }

  // ---- rotated-chunk LDS epilogue ----
  __syncthreads();
  u16* scr = lds;                        // 128 x 128 u16 = 32 KB
  const int g = l >> 4;
  const int rbase = g * 4;
#pragma unroll
  for (int mi = 0; mi < 4; ++mi) {
#pragma unroll
    for (int ni = 0; ni < 2; ++ni) {
      int lr0 = wm * 64 + mi * 16 + rbase;
      int lc = wn * 32 + ni * 16 + fr;
      int col = (((lc >> 3) + 2 * g) & 15) * 8 + (lc & 7);
      float s0 = silu_f(acc[mi][ni][0]);
      float s1 = silu_f(acc[mi][ni][1]);
      float s2 = silu_f(acc[mi][ni][2]);
      float s3 = silu_f(acc[mi][ni][3]);
      unsigned p01 = cvtpk_bf16(s0, s1);
      unsigned p23 = cvtpk_bf16(s2, s3);
      scr[(lr0 + 0) * 128 + col] = (u16)p01;
      scr[(lr0 + 1) * 128 + col] = (u16)(p01 >> 16);
      scr[(lr0 + 2) * 128 + col] = (u16)p23;
      scr[(lr0 + 3) * 128 + col] = (u16)(p23 >> 16);
    }
  }
  __syncthreads();
  u16* Cw = (n0 < 512) ? u_bf : sr_bf;
  const int cb = (n0 < 512) ? n0 : (n0 - 512);
#pragma unroll
  for (int r = 0; r < 4; ++r) {
    int row = (tid >> 4) + r * 32;
    int c = tid & 15;
    int pc = (c + 2 * ((row >> 2) & 3)) & 15;
    uint4 v = *(const uint4*)&scr[row * 128 + pc * 8];
    *(uint4*)&Cw[(size_t)(m0 + row) * 512 + cb + c * 8] = v;
  }
}

// ------------- 16-wave MFMA GEMM: 128x256 tile, BK=32, 1024 threads -------------
// Waves 0-7 stage A (gld_lds), waves 8-15 stage B (2 gld_lds). 3 bufs, depth-2,
// per-wave counted vmcnt (A:1, B:2).
// MODE 2: g tile via rotated-chunk bf16 epilogue [128][256] (big 67MB stream)
// MODE 3: fp32 out via DIRECT stores (64B segments; LDS 2-pass measured slower)
template<int MODE, int LOG_NBX, int KDIM>
__global__ __launch_bounds__(1024) void mgemm2(
    const u16* __restrict__ Ain, const u16* __restrict__ Bt,
    void* __restrict__ C0, void* __restrict__ C1,
    const float* __restrict__ Dvec) {
  constexpr int NT = KDIM / 32;
  __shared__ u16 lds[36864];             // 72 KB: As[3] | Bs[3]; scratch aliases
  u16* AsB = lds;
  u16* BsB = lds + 12288;
  const int tid = threadIdx.x;
  const int w = tid >> 6, l = tid & 63;
  const int wm = w >> 3, wn = w & 7;
  const bool isA = (w < 8);

  const int lin = blockIdx.x;
  const int cpx = gridDim.x >> 3;
  const int swz = (lin & 7) * cpx + (lin >> 3);
  const int n0 = (swz & ((1 << LOG_NBX) - 1)) * 256;
  const int m0 = (swz >> LOG_NBX) * 128;

  f32x4 acc[4][2] = {};

  const int fr = l & 15;
  const int kgs = (((l >> 4) ^ (l >> 1)) & 3) * 8;
  const int sr = l >> 2;
  const int scs = (l & 3) ^ ((l >> 3) & 3);

  const u16* gA = nullptr;
  const u16* gB = nullptr;
  if (isA) gA = Ain + (size_t)(m0 + w * 16 + sr) * KDIM + scs * 8;
  else     gB = Bt + (size_t)(n0 + (w - 8) * 16 + sr) * KDIM + scs * 8;

  auto stage = [&](int buf, int k0) {
    if (isA) {
      gld16(gA + k0, &AsB[buf * 4096 + w * 512]);
    } else {
      gld16(gB + k0, &BsB[buf * 8192 + (w - 8) * 512]);
      gld16(gB + k0 + (size_t)128 * KDIM, &BsB[buf * 8192 + (w - 8) * 512 + 4096]);
    }
  };
  auto compute = [&](int buf) {
    short8v af[4], bfr[2];
#pragma unroll
    for (int mi = 0; mi < 4; ++mi)
      af[mi] = *(const short8v*)&AsB[buf * 4096 + (wm * 64 + mi * 16 + fr) * 32 + kgs];
#pragma unroll
    for (int ni = 0; ni < 2; ++ni)
      bfr[ni] = *(const short8v*)&BsB[buf * 8192 + (wn * 32 + ni * 16 + fr) * 32 + kgs];
#pragma unroll
    for (int mi = 0; mi < 4; ++mi)
#pragma unroll
      for (int ni = 0; ni < 2; ++ni)
        acc[mi][ni] = __builtin_amdgcn_mfma_f32_16x16x32_bf16(af[mi], bfr[ni], acc[mi][ni], 0, 0, 0);
  };

  stage(0, 0);
  stage(1, 32);
#pragma unroll
  for (int t = 0; t < NT; ++t) {
    if (t + 1 < NT) { if (isA) { WAITV1; } else { WAITV2; } } else { WAITV0; }
    BARRAW;
    if (t + 2 < NT) stage((t + 2) % 3, (t + 2) * 32);
    compute(t % 3);
  }

  const int g = l >> 4;
  const int rbase = g * 4;
  if (MODE == 2) {
    // ---- rotated-chunk bf16 epilogue: [128][256] u16 = 64 KB ----
    __syncthreads();
    u16* scr = lds;
#pragma unroll
    for (int mi = 0; mi < 4; ++mi) {
#pragma unroll
      for (int ni = 0; ni < 2; ++ni) {
        int lr0 = wm * 64 + mi * 16 + rbase;
        int lc = wn * 32 + ni * 16 + fr;
        int col = (((lc >> 3) + 2 * g) & 31) * 8 + (lc & 7);
        int gr0 = m0 + lr0;
        int gc = n0 + lc;
        float gg[4];
#pragma unroll
        for (int j = 0; j < 4; ++j) {
          size_t r = (size_t)(gr0 + j);
          float uu = bf2f(((const u16*)C0)[r * 512 + gc]);
          float sr2 = bf2f(((const u16*)C1)[r * 512 + gc]);
          gg[j] = (acc[mi][ni][j] + Dvec[gc] * uu) * sr2;
        }
        unsigned p01 = cvtpk_bf16(gg[0], gg[1]);
        unsigned p23 = cvtpk_bf16(gg[2], gg[3]);
        scr[(lr0 + 0) * 256 + col] = (u16)p01;
        scr[(lr0 + 1) * 256 + col] = (u16)(p01 >> 16);
        scr[(lr0 + 2) * 256 + col] = (u16)p23;
        scr[(lr0 + 3) * 256 + col] = (u16)(p23 >> 16);
      }
    }
    __syncthreads();
#pragma unroll
    for (int r = 0; r < 4; ++r) {
      int row = (tid >> 5) + r * 32;
      int c = tid & 31;
      int pc = (c + 2 * ((row >> 2) & 3)) & 31;
      uint4 v = *(const uint4*)&scr[row * 256 + pc * 8];
      *(uint4*)&((u16*)C1)[(size_t)(m0 + row) * 512 + n0 + c * 8] = v;
    }
  } else {
    // ---- direct fp32 stores (R12-measured-best for this stream) ----
#pragma unroll
    for (int mi = 0; mi < 4; ++mi) {
#pragma unroll
      for (int ni = 0; ni < 2; ++ni) {
        int gr0 = m0 + wm * 64 + mi * 16 + rbase;
        int gc = n0 + wn * 32 + ni * 16 + fr;
#pragma unroll
        for (int j = 0; j < 4; ++j)
          ((float*)C0)[(size_t)(gr0 + j) * 256 + gc] = acc[mi][ni][j];
      }
    }
  }
}

// ---------------- K2: Bu(bf16) = u @ dB^T + fused chunk carry-sum ----------
// Bu via direct scalar stores (16-lane 32B segments; small 16.7MB stream —
// LDS roundtrip measured slower in R15). Carry sums fp32.
__global__ __launch_bounds__(512) void k2_bu_carry(
    const u16* __restrict__ A, const u16* __restrict__ Bt,
    u16* __restrict__ Bu, float* __restrict__ carr, float* __restrict__ carr2,
    const float2* __restrict__ dAf, const float2* __restrict__ powt) {
  constexpr int KDIM = 512;
  constexpr int NT = KDIM / 32;
  __shared__ u16 As[3][128 * 32];
  __shared__ u16 Bs[3][128 * 32];
  const int tid = threadIdx.x;
  const int w = tid >> 6, l = tid & 63;
  const int wm = w >> 2, wn = w & 3;

  const int lin = blockIdx.x;
  const int cpx = gridDim.x >> 3;
  const int swz = (lin & 7) * cpx + (lin >> 3);
  const int m0 = swz * 128;

  f32x4 acc[4][2] = {};

  const int lr = l >> 2;
  const int sc = (l & 3) ^ ((l >> 3) & 3);
  const u16* gA = A + (size_t)(m0 + w * 16 + lr) * KDIM + sc * 8;
  const u16* gB = Bt + (size_t)(w * 16 + lr) * KDIM + sc * 8;

  const int fr = l & 15;
  const int kgs = (((l >> 4) ^ (l >> 1)) & 3) * 8;

  auto stage = [&](int buf, int k0) {
    gld16(gA + k0, &As[buf][w * 512]);
    gld16(gB + k0, &Bs[buf][w * 512]);
  };
  auto compute = [&](int buf) {
    short8v af[4], bfr[2];
#pragma unroll
    for (int mi = 0; mi < 4; ++mi)
      af[mi] = *(const short8v*)&As[buf][(wm * 64 + mi * 16 + fr) * 32 + kgs];
#pragma unroll
    for (int ni = 0; ni < 2; ++ni)
      bfr[ni] = *(const short8v*)&Bs[buf][(wn * 32 + ni * 16 + fr) * 32 + kgs];
#pragma unroll
    for (int mi = 0; mi < 4; ++mi)
#pragma unroll
      for (int ni = 0; ni < 2; ++ni)
        acc[mi][ni] = __builtin_amdgcn_mfma_f32_16x16x32_bf16(af[mi], bfr[ni], acc[mi][ni], 0, 0, 0);
  };

  stage(0, 0);
  stage(1, 32);
#pragma unroll
  for (int t = 0; t < NT; ++t) {
    if (t + 1 < NT) { WAITV2; } else { WAITV0; }
    BARRAW;
    if (t + 2 < NT) stage((t + 2) % 3, (t + 2) * 32);
    compute(t % 3);
  }

  const int g = l >> 4;
  const int rbase = g * 4;
#pragma unroll
  for (int mi = 0; mi < 4; ++mi)
#pragma unroll
    for (int ni = 0; ni < 2; ++ni) {
      int gr0 = m0 + wm * 64 + mi * 16 + rbase;
      int gc = wn * 32 + ni * 16 + fr;
#pragma unroll
      for (int j = 0; j < 4; ++j)
        Bu[(size_t)(gr0 + j) * 128 + gc] = f2bf(acc[mi][ni][j]);
    }
  // fused chunk carry-sum: carr[chunk] = sum_r dA^{63-r} Bu_r  (fp32 accs)
  const int cu = (m0 >> 6) + wm;
#pragma unroll
  for (int ni = 0; ni < 2; ++ni) {
    int gc = wn * 32 + ni * 16 + fr;
    int p = gc & 63;
    float2 dA = dAf[p];
    float sre = 0.f, sim = 0.f;
#pragma unroll
    for (int mi = 0; mi < 4; ++mi) {
      float tr = 0.f, ti = 0.f;
#pragma unroll
      for (int j = 0; j < 4; ++j) {
        float v = acc[mi][ni][j];
        float nr = fmaf(dA.x, tr, fmaf(-dA.y, ti, v));
        float nim = fmaf(dA.x, ti, dA.y * tr);
        tr = nr; ti = nim;
      }
      float2 wg = powt[p * (GCH + 1) + 60 - g * 4 - 16 * mi];
      sre = fmaf(wg.x, tr, fmaf(-wg.y, ti, sre));
      sim = fmaf(wg.x, ti, fmaf(wg.y, tr, sim));
    }
    sre += __shfl_xor(sre, 16); sim += __shfl_xor(sim, 16);
    sre += __shfl_xor(sre, 32); sim += __shfl_xor(sim, 32);
    if (g == 0) {
      size_t crow = (size_t)cu * 128;
      if (gc < 64) { carr[crow + p] = sre;  carr[crow + 64 + p] = sim; }
      else         { carr2[crow + p] = -sim; carr2[crow + 64 + p] = sre; }
    }
  }
}

// ---------------- K3b: chunk-carry exclusive prefix scan (pipelined) ----------
__global__ void scan_carry_k(const float* __restrict__ carr, const float* __restrict__ carr2,
                             float* __restrict__ offc, const float2* __restrict__ powt) {
  int b = threadIdx.x >> 6;
  int p = threadIdx.x & 63;
  float2 dAG = powt[p * (GCH + 1) + GCH];   // dA^G
  float rr = 0.f, ri = 0.f;
  float a0[8], b0[8], c0a[8], d0a[8];
  float a1[8], b1[8], c1a[8], d1a[8];

#define LOADB(cb, A_, B_, C_, D_)                                      \
  {                                                                     \
    _Pragma("unroll") for (int j = 0; j < 8; ++j) {                     \
      size_t crow = (size_t)(b * NCH + (cb) + j) * 128;                 \
      A_[j] = carr[crow + p]; B_[j] = carr[crow + 64 + p];              \
      C_[j] = carr2[crow + p]; D_[j] = carr2[crow + 64 + p];            \
    }                                                                   \
  }
#define STEPB(cb, A_, B_, C_, D_)                                      \
  {                                                                     \
    _Pragma("unroll") for (int j = 0; j < 8; ++j) {                     \
      size_t orow = (size_t)(b * NCH + (cb) + j) * 128;                 \
      offc[orow + p] = rr; offc[orow + 64 + p] = ri;                    \
      float er = A_[j] + C_[j], ei = B_[j] + D_[j];                     \
      float nr = fmaf(dAG.x, rr, fmaf(-dAG.y, ri, er));                 \
      float ni = fmaf(dAG.x, ri, fmaf(dAG.y, rr, ei));                  \
      rr = nr; ri = ni;                                                 \
    }                                                                   \
  }

  LOADB(0, a0, b0, c0a, d0a);
  for (int c0 = 0; c0 < NCH; c0 += 16) {
    LOADB(c0 + 8, a1, b1, c1a, d1a);
    STEPB(c0, a0, b0, c0a, d0a);
    if (c0 + 16 < NCH) LOADB(c0 + 16, a0, b0, c0a, d0a);
    STEPB(c0 + 8, a1, b1, c1a, d1a);
  }
#undef LOADB
#undef STEPB
}

// ---------------- K3c: seeded local scan (bf16 Bu in), emits bf16 h ------------
__global__ __launch_bounds__(256) void scan_emit_k(const u16* __restrict__ Bu,
                                                   const float* __restrict__ offc,
                                                   u16* __restrict__ hb,
                                                   const float2* __restrict__ dAf) {
  int unit = blockIdx.x * 4 + (threadIdx.x >> 6);   // b*NCH + c
  int p = threadIdx.x & 63;
  int b = unit >> 8, c = unit & 255;
  float2 dA = dAf[p];
  size_t base = ((size_t)b * LSEQ + (size_t)c * GCH) * 128;
  float hr = offc[(size_t)unit * 128 + p];
  float hi = offc[(size_t)unit * 128 + 64 + p];
  for (int i0 = 0; i0 < GCH; i0 += 8) {
    float br[8], bi[8];
#pragma unroll
    for (int j = 0; j < 8; ++j) {
      br[j] = bf2f(Bu[base + (size_t)(i0 + j) * 128 + p]);
      bi[j] = bf2f(Bu[base + (size_t)(i0 + j) * 128 + 64 + p]);
    }
#pragma unroll
    for (int j = 0; j < 8; ++j) {
      float nr = fmaf(dA.x, hr, fmaf(-dA.y, hi, br[j]));
      float ni = fmaf(dA.x, hi, fmaf(dA.y, hr, bi[j]));
      hr = nr; hi = ni;
      hb[base + (size_t)(i0 + j) * 128 + p] = f2bf(hr);
      hb[base + (size_t)(i0 + j) * 128 + 64 + p] = f2bf(hi);
    }
  }
}

extern "C" void kernel_launch(void* const* d_in, const int* in_sizes, int n_in,
                              void* d_out, int out_size, void* d_ws, size_t ws_size,
                              hipStream_t stream) {
  const float* x      = (const float*)d_in[0];
  const float* W_in   = (const float*)d_in[1];
  const float* W_out  = (const float*)d_in[2];
  const float* A_real = (const float*)d_in[3];
  const float* A_imag = (const float*)d_in[4];
  const float* B_re   = (const float*)d_in[5];
  const float* B_im   = (const float*)d_in[6];
  const float* C_re   = (const float*)d_in[7];
  const float* C_im   = (const float*)d_in[8];
  const float* Dv     = (const float*)d_in[9];
  const float* inv_dt = (const float*)d_in[10];

  // ---- workspace layout (bf16 buffers) ----
  u16* xb    = (u16*)d_ws;                       // N*256
  u16* u_bf  = xb + (size_t)NTOK * 256;          // N*512
  u16* sr_bf = u_bf + (size_t)NTOK * 512;        // N*512 (becomes g after K4a)
  u16* h_bf  = sr_bf + (size_t)NTOK * 512;       // N*128
  u16* WinT  = h_bf + (size_t)NTOK * 128;        // 1024*256
  u16* dBn   = WinT + 1024 * 256;                // 128*512
  u16* Ccb   = dBn + 128 * 512;                  // 512*128
  u16* WoutT = Ccb + 512 * 128;                  // 256*512

  // ---- d_out doubles as scratch (dead before final GEMM writes it) ----
  float* O    = (float*)d_out;
  u16* Bu     = (u16*)O;                  // N*128 u16 = 4194304 float-slots
  float* offc = O + 4194304;              // 1024*128
  float* carr = O + 4325376;              // 1024*128
  float* car2 = O + 4456448;              // 1024*128
  float2* powt = (float2*)(O + 4587520);  // 64*65 float2
  float2* dAf  = (float2*)(O + 4595840);  // 64 float2
  float2* fvec = (float2*)(O + 4595968);  // 64 float2

  setup_scalar_k<<<1, 64, 0, stream>>>(A_real, A_imag, inv_dt, dAf, fvec, powt);
  setup_tables_k<<<256, 256, 0, stream>>>(B_re, B_im, C_re, C_im, W_in, W_out, fvec,
                                          WinT, dBn, Ccb, WoutT);
  cvt_x_k<<<2048, 256, 0, stream>>>(x, xb);

  // K1: [u|res] = silu(x @ W_in)  (512 m-tiles x 8 col-tiles)
  k1_gemm<<<4096, 512, 0, stream>>>(xb, WinT, u_bf, sr_bf);
  // K2: Bu = u @ dB^T (bf16) + fused chunk carry
  k2_bu_carry<<<512, 512, 0, stream>>>(u_bf, dBn, Bu, carr, car2, dAf, powt);
  // K3: carry prefix scan + seeded local scan -> bf16 h
  scan_carry_k<<<1, 256, 0, stream>>>(carr, car2, offc, powt);
  scan_emit_k<<<256, 256, 0, stream>>>(Bu, offc, h_bf, dAf);
  // K4a: g = (Re(h C^T) + D*u) * sres  (512 m-tiles x 2 n-tiles)
  mgemm2<2, 1, 128><<<1024, 1024, 0, stream>>>(h_bf, Ccb, u_bf, sr_bf, Dv);
  // K4b: out = g @ W_out  (512 m-tiles x 1 n-tile)
  mgemm2<3, 0, 512><<<512, 1024, 0, stream>>>(sr_bf, WoutT, O, nullptr, nullptr);
}

// Round 18
// 195.619 us; speedup vs baseline: 1.0728x; 1.0229x over previous
//
#include <hip/hip_runtime.h>
#include <math.h>

#define NTOK 65536
#define LSEQ 16384
#define GCH 64
#define NCH 256   // LSEQ / GCH

typedef __attribute__((ext_vector_type(8))) short short8v;
typedef __attribute__((ext_vector_type(4))) float f32x4;
typedef unsigned short u16;

__device__ __forceinline__ u16 f2bf(float f) {
  unsigned u = __float_as_uint(f);
  return (u16)((u + 0x7FFFu + ((u >> 16) & 1u)) >> 16);
}
__device__ __forceinline__ float bf2f(u16 b) {
  return __uint_as_float(((unsigned)b) << 16);
}
__device__ __forceinline__ unsigned cvtpk_bf16(float lo, float hi) {
  unsigned r;
  asm("v_cvt_pk_bf16_f32 %0, %1, %2" : "=v"(r) : "v"(lo), "v"(hi));
  return r;
}
__device__ __forceinline__ float silu_f(float v) {
  return v * __builtin_amdgcn_rcpf(1.f + __expf(-v));
}
__device__ __forceinline__ void gld16(const u16* g, u16* l) {
  __builtin_amdgcn_global_load_lds((const __attribute__((address_space(1))) void*)g,
                                   (__attribute__((address_space(3))) void*)l, 16, 0, 0);
}

#define WAITV2 asm volatile("s_waitcnt vmcnt(2) lgkmcnt(0)" ::: "memory")
#define WAITV1 asm volatile("s_waitcnt vmcnt(1) lgkmcnt(0)" ::: "memory")
#define WAITV0 asm volatile("s_waitcnt vmcnt(0) lgkmcnt(0)" ::: "memory")
#define BARRAW asm volatile("s_barrier" ::: "memory")

// ---------------- K0a: scalar SSM parameter setup (fp64) ----------------
__global__ void setup_scalar_k(const float* __restrict__ A_real, const float* __restrict__ A_imag,
                               const float* __restrict__ inv_dt,
                               float2* __restrict__ dAf, float2* __restrict__ fvec,
                               float2* __restrict__ powt) {
  int p = threadIdx.x;
  if (p >= 64) return;
  double ar = (double)A_real[p], ai = (double)A_imag[p];
  double dt = log1p(exp((double)inv_dt[p]));   // softplus
  double zr = 0.5 * dt * ar, zi = 0.5 * dt * ai;
  double d1r = 1.0 - zr;
  double den = d1r * d1r + zi * zi;
  double blr = d1r / den, bli = zi / den;      // BL = 1/(1-z)
  double nr = 1.0 + zr, ni = zi;               // 1+z
  double dar = blr * nr - bli * ni;            // dA
  double dai = blr * ni + bli * nr;
  dAf[p] = make_float2((float)dar, (float)dai);
  fvec[p] = make_float2((float)(blr * dt), (float)(bli * dt));   // f = BL*dt
  double cr = 1.0, ci = 0.0;
  for (int k = 0; k <= GCH; ++k) {
    powt[p * (GCH + 1) + k] = make_float2((float)cr, (float)ci); // dA^k
    double t = cr * dar - ci * dai;
    ci = cr * dai + ci * dar;
    cr = t;
  }
}

// ---------------- K0b: build bf16 B^T-layout weight tables ----------------
__global__ void setup_tables_k(const float* __restrict__ B_re, const float* __restrict__ B_im,
                               const float* __restrict__ C_re, const float* __restrict__ C_im,
                               const float* __restrict__ W_in, const float* __restrict__ W_out,
                               const float2* __restrict__ fvec,
                               u16* __restrict__ WinT, u16* __restrict__ dBn,
                               u16* __restrict__ Ccb, u16* __restrict__ WoutT) {
  int idx = blockIdx.x * blockDim.x + threadIdx.x;
  int stride = gridDim.x * blockDim.x;
  // WinT [1024][256]
  for (int i = idx; i < 1024 * 256; i += stride) {
    int n = i >> 8, k = i & 255;
    WinT[i] = f2bf(W_in[k * 1024 + n]);
  }
  // dBn [128][512]  (rows 0-63 Re(dB), 64-127 Im(dB))
  for (int i = idx; i < 128 * 512; i += stride) {
    int p = i >> 9, d = i & 511;
    float2 f = fvec[p & 63];
    float br = B_re[(p & 63) * 512 + d], bi = B_im[(p & 63) * 512 + d];
    float v = (p < 64) ? (f.x * br - f.y * bi) : (f.x * bi + f.y * br);
    dBn[i] = f2bf(v);
  }
  // Ccb [512][128]  (cols 0-63: C_re, 64-127: -C_im)
  for (int i = idx; i < 512 * 128; i += stride) {
    int d = i >> 7, k = i & 127;
    float v = (k < 64) ? C_re[d * 64 + k] : -C_im[d * 64 + (k - 64)];
    Ccb[i] = f2bf(v);
  }
  // WoutT [256][512]
  for (int i = idx; i < 256 * 512; i += stride) {
    int n = i >> 9, k = i & 511;
    WoutT[i] = f2bf(W_out[k * 256 + n]);
  }
}

// ---------------- x -> bf16 ----------------
__global__ __launch_bounds__(256) void cvt_x_k(const float* __restrict__ x, u16* __restrict__ xb) {
  size_t i = ((size_t)blockIdx.x * blockDim.x + threadIdx.x) * 4;
  size_t stride = (size_t)gridDim.x * blockDim.x * 4;
  const size_t total = (size_t)NTOK * 256;
  for (; i < total; i += stride) {
    float4 v = *(const float4*)(x + i);
    ushort4 o;
    o.x = f2bf(v.x); o.y = f2bf(v.y); o.z = f2bf(v.z); o.w = f2bf(v.w);
    *(ushort4*)(xb + i) = o;
  }
}

// ---------------- K1: [u|res] = silu(xb @ WinT) — rotated-chunk epilogue -------
// 8 waves (2x4), 128x128 tile, BK=32, NT=8, gld_lds both operands, 3 LDS bufs,
// depth-2 counted vmcnt(2). Rotated-chunk scratch: conflict-free + aligned.
__global__ __launch_bounds__(512) void k1_gemm(
    const u16* __restrict__ A, const u16* __restrict__ Bt,
    u16* __restrict__ u_bf, u16* __restrict__ sr_bf) {
  constexpr int KDIM = 256, NT = 8;
  __shared__ u16 lds[24576];             // 48 KB: As[3] | Bs[3]; scratch aliases
  u16* AsB = lds;
  u16* BsB = lds + 12288;
  const int tid = threadIdx.x;
  const int w = tid >> 6, l = tid & 63;
  const int wm = w >> 2, wn = w & 3;

  const int lin = blockIdx.x;
  const int cpx = gridDim.x >> 3;
  const int swz = (lin & 7) * cpx + (lin >> 3);
  const int n0 = (swz & 7) * 128;
  const int m0 = (swz >> 3) * 128;

  f32x4 acc[4][2] = {};

  const int lr = l >> 2;
  const int sc = (l & 3) ^ ((l >> 3) & 3);
  const u16* gA = A + (size_t)(m0 + w * 16 + lr) * KDIM + sc * 8;
  const u16* gB = Bt + (size_t)(n0 + w * 16 + lr) * KDIM + sc * 8;

  const int fr = l & 15;
  const int kgs = (((l >> 4) ^ (l >> 1)) & 3) * 8;

  auto stage = [&](int buf, int k0) {
    gld16(gA + k0, &AsB[buf * 4096 + w * 512]);
    gld16(gB + k0, &BsB[buf * 4096 + w * 512]);
  };
  auto compute = [&](int buf) {
    short8v af[4], bfr[2];
#pragma unroll
    for (int mi = 0; mi < 4; ++mi)
      af[mi] = *(const short8v*)&AsB[buf * 4096 + (wm * 64 + mi * 16 + fr) * 32 + kgs];
#pragma unroll
    for (int ni = 0; ni < 2; ++ni)
      bfr[ni] = *(const short8v*)&BsB[buf * 4096 + (wn * 32 + ni * 16 + fr) * 32 + kgs];
#pragma unroll
    for (int mi = 0; mi < 4; ++mi)
#pragma unroll
      for (int ni = 0; ni < 2; ++ni)
        acc[mi][ni] = __builtin_amdgcn_mfma_f32_16x16x32_bf16(af[mi], bfr[ni], acc[mi][ni], 0, 0, 0);
  };

  stage(0, 0);
  stage(1, 32);
#pragma unroll
  for (int t = 0; t < NT; ++t) {
    if (t + 1 < NT) { WAITV2; } else { WAITV0; }
    BARRAW;
    if (t + 2 < NT) stage((t + 2) % 3, (t + 2) * 32);
    compute(t % 3);
  }

  // ---- rotated-chunk LDS epilogue ----
  __syncthreads();
  u16* scr = lds;                        // 128 x 128 u16 = 32 KB
  const int g = l >> 4;
  const int rbase = g * 4;
#pragma unroll
  for (int mi = 0; mi < 4; ++mi) {
#pragma unroll
    for (int ni = 0; ni < 2; ++ni) {
      int lr0 = wm * 64 + mi * 16 + rbase;
      int lc = wn * 32 + ni * 16 + fr;
      int col = (((lc >> 3) + 2 * g) & 15) * 8 + (lc & 7);
      float s0 = silu_f(acc[mi][ni][0]);
      float s1 = silu_f(acc[mi][ni][1]);
      float s2 = silu_f(acc[mi][ni][2]);
      float s3 = silu_f(acc[mi][ni][3]);
      unsigned p01 = cvtpk_bf16(s0, s1);
      unsigned p23 = cvtpk_bf16(s2, s3);
      scr[(lr0 + 0) * 128 + col] = (u16)p01;
      scr[(lr0 + 1) * 128 + col] = (u16)(p01 >> 16);
      scr[(lr0 + 2) * 128 + col] = (u16)p23;
      scr[(lr0 + 3) * 128 + col] = (u16)(p23 >> 16);
    }
  }
  __syncthreads();
  u16* Cw = (n0 < 512) ? u_bf : sr_bf;
  const int cb = (n0 < 512) ? n0 : (n0 - 512);
#pragma unroll
  for (int r = 0; r < 4; ++r) {
    int row = (tid >> 4) + r * 32;
    int c = tid & 15;
    int pc = (c + 2 * ((row >> 2) & 3)) & 15;
    uint4 v = *(const uint4*)&scr[row * 128 + pc * 8];
    *(uint4*)&Cw[(size_t)(m0 + row) * 512 + cb + c * 8] = v;
  }
}

// ------------- 16-wave MFMA GEMM: 128x256 tile, BK=32, 1024 threads -------------
// Waves 0-7 stage A (gld_lds), waves 8-15 stage B (2 gld_lds). 3 bufs, depth-2,
// per-wave counted vmcnt (A:1, B:2).
// MODE 2: g tile via rotated-chunk bf16 epilogue [128][256] (gate in staging
//         phase — R17's gate-in-store variant NaN'd, reverted)
// MODE 3: fp32 out via direct stores
template<int MODE, int LOG_NBX, int KDIM>
__global__ __launch_bounds__(1024) void mgemm2(
    const u16* __restrict__ Ain, const u16* __restrict__ Bt,
    void* __restrict__ C0, void* __restrict__ C1,
    const float* __restrict__ Dvec) {
  constexpr int NT = KDIM / 32;
  __shared__ u16 lds[36864];             // 72 KB: As[3] | Bs[3]; scratch aliases
  u16* AsB = lds;
  u16* BsB = lds + 12288;
  const int tid = threadIdx.x;
  const int w = tid >> 6, l = tid & 63;
  const int wm = w >> 3, wn = w & 7;
  const bool isA = (w < 8);

  const int lin = blockIdx.x;
  const int cpx = gridDim.x >> 3;
  const int swz = (lin & 7) * cpx + (lin >> 3);
  const int n0 = (swz & ((1 << LOG_NBX) - 1)) * 256;
  const int m0 = (swz >> LOG_NBX) * 128;

  f32x4 acc[4][2] = {};

  const int fr = l & 15;
  const int kgs = (((l >> 4) ^ (l >> 1)) & 3) * 8;
  const int sr = l >> 2;
  const int scs = (l & 3) ^ ((l >> 3) & 3);

  const u16* gA = nullptr;
  const u16* gB = nullptr;
  if (isA) gA = Ain + (size_t)(m0 + w * 16 + sr) * KDIM + scs * 8;
  else     gB = Bt + (size_t)(n0 + (w - 8) * 16 + sr) * KDIM + scs * 8;

  auto stage = [&](int buf, int k0) {
    if (isA) {
      gld16(gA + k0, &AsB[buf * 4096 + w * 512]);
    } else {
      gld16(gB + k0, &BsB[buf * 8192 + (w - 8) * 512]);
      gld16(gB + k0 + (size_t)128 * KDIM, &BsB[buf * 8192 + (w - 8) * 512 + 4096]);
    }
  };
  auto compute = [&](int buf) {
    short8v af[4], bfr[2];
#pragma unroll
    for (int mi = 0; mi < 4; ++mi)
      af[mi] = *(const short8v*)&AsB[buf * 4096 + (wm * 64 + mi * 16 + fr) * 32 + kgs];
#pragma unroll
    for (int ni = 0; ni < 2; ++ni)
      bfr[ni] = *(const short8v*)&BsB[buf * 8192 + (wn * 32 + ni * 16 + fr) * 32 + kgs];
#pragma unroll
    for (int mi = 0; mi < 4; ++mi)
#pragma unroll
      for (int ni = 0; ni < 2; ++ni)
        acc[mi][ni] = __builtin_amdgcn_mfma_f32_16x16x32_bf16(af[mi], bfr[ni], acc[mi][ni], 0, 0, 0);
  };

  stage(0, 0);
  stage(1, 32);
#pragma unroll
  for (int t = 0; t < NT; ++t) {
    if (t + 1 < NT) { if (isA) { WAITV1; } else { WAITV2; } } else { WAITV0; }
    BARRAW;
    if (t + 2 < NT) stage((t + 2) % 3, (t + 2) * 32);
    compute(t % 3);
  }

  const int g = l >> 4;
  const int rbase = g * 4;
  if (MODE == 2) {
    // ---- rotated-chunk bf16 epilogue: [128][256] u16 = 64 KB ----
    __syncthreads();
    u16* scr = lds;
#pragma unroll
    for (int mi = 0; mi < 4; ++mi) {
#pragma unroll
      for (int ni = 0; ni < 2; ++ni) {
        int lr0 = wm * 64 + mi * 16 + rbase;
        int lc = wn * 32 + ni * 16 + fr;
        int col = (((lc >> 3) + 2 * g) & 31) * 8 + (lc & 7);
        int gr0 = m0 + lr0;
        int gc = n0 + lc;
        float gg[4];
#pragma unroll
        for (int j = 0; j < 4; ++j) {
          size_t r = (size_t)(gr0 + j);
          float uu = bf2f(((const u16*)C0)[r * 512 + gc]);
          float sr2 = bf2f(((const u16*)C1)[r * 512 + gc]);
          gg[j] = (acc[mi][ni][j] + Dvec[gc] * uu) * sr2;
        }
        unsigned p01 = cvtpk_bf16(gg[0], gg[1]);
        unsigned p23 = cvtpk_bf16(gg[2], gg[3]);
        scr[(lr0 + 0) * 256 + col] = (u16)p01;
        scr[(lr0 + 1) * 256 + col] = (u16)(p01 >> 16);
        scr[(lr0 + 2) * 256 + col] = (u16)p23;
        scr[(lr0 + 3) * 256 + col] = (u16)(p23 >> 16);
      }
    }
    __syncthreads();
#pragma unroll
    for (int r = 0; r < 4; ++r) {
      int row = (tid >> 5) + r * 32;
      int c = tid & 31;
      int pc = (c + 2 * ((row >> 2) & 3)) & 31;
      uint4 v = *(const uint4*)&scr[row * 256 + pc * 8];
      *(uint4*)&((u16*)C1)[(size_t)(m0 + row) * 512 + n0 + c * 8] = v;
    }
  } else {
    // ---- direct fp32 stores ----
#pragma unroll
    for (int mi = 0; mi < 4; ++mi) {
#pragma unroll
      for (int ni = 0; ni < 2; ++ni) {
        int gr0 = m0 + wm * 64 + mi * 16 + rbase;
        int gc = n0 + wn * 32 + ni * 16 + fr;
#pragma unroll
        for (int j = 0; j < 4; ++j)
          ((float*)C0)[(size_t)(gr0 + j) * 256 + gc] = acc[mi][ni][j];
      }
    }
  }
}

// ---------------- K2: Bu(bf16) = u @ dB^T + fused chunk carry-sum ----------
__global__ __launch_bounds__(512) void k2_bu_carry(
    const u16* __restrict__ A, const u16* __restrict__ Bt,
    u16* __restrict__ Bu, float* __restrict__ carr, float* __restrict__ carr2,
    const float2* __restrict__ dAf, const float2* __restrict__ powt) {
  constexpr int KDIM = 512;
  constexpr int NT = KDIM / 32;
  __shared__ u16 As[3][128 * 32];
  __shared__ u16 Bs[3][128 * 32];
  const int tid = threadIdx.x;
  const int w = tid >> 6, l = tid & 63;
  const int wm = w >> 2, wn = w & 3;

  const int lin = blockIdx.x;
  const int cpx = gridDim.x >> 3;
  const int swz = (lin & 7) * cpx + (lin >> 3);
  const int m0 = swz * 128;

  f32x4 acc[4][2] = {};

  const int lr = l >> 2;
  const int sc = (l & 3) ^ ((l >> 3) & 3);
  const u16* gA = A + (size_t)(m0 + w * 16 + lr) * KDIM + sc * 8;
  const u16* gB = Bt + (size_t)(w * 16 + lr) * KDIM + sc * 8;

  const int fr = l & 15;
  const int kgs = (((l >> 4) ^ (l >> 1)) & 3) * 8;

  auto stage = [&](int buf, int k0) {
    gld16(gA + k0, &As[buf][w * 512]);
    gld16(gB + k0, &Bs[buf][w * 512]);
  };
  auto compute = [&](int buf) {
    short8v af[4], bfr[2];
#pragma unroll
    for (int mi = 0; mi < 4; ++mi)
      af[mi] = *(const short8v*)&As[buf][(wm * 64 + mi * 16 + fr) * 32 + kgs];
#pragma unroll
    for (int ni = 0; ni < 2; ++ni)
      bfr[ni] = *(const short8v*)&Bs[buf][(wn * 32 + ni * 16 + fr) * 32 + kgs];
#pragma unroll
    for (int mi = 0; mi < 4; ++mi)
#pragma unroll
      for (int ni = 0; ni < 2; ++ni)
        acc[mi][ni] = __builtin_amdgcn_mfma_f32_16x16x32_bf16(af[mi], bfr[ni], acc[mi][ni], 0, 0, 0);
  };

  stage(0, 0);
  stage(1, 32);
#pragma unroll
  for (int t = 0; t < NT; ++t) {
    if (t + 1 < NT) { WAITV2; } else { WAITV0; }
    BARRAW;
    if (t + 2 < NT) stage((t + 2) % 3, (t + 2) * 32);
    compute(t % 3);
  }

  const int g = l >> 4;
  const int rbase = g * 4;
#pragma unroll
  for (int mi = 0; mi < 4; ++mi)
#pragma unroll
    for (int ni = 0; ni < 2; ++ni) {
      int gr0 = m0 + wm * 64 + mi * 16 + rbase;
      int gc = wn * 32 + ni * 16 + fr;
#pragma unroll
      for (int j = 0; j < 4; ++j)
        Bu[(size_t)(gr0 + j) * 128 + gc] = f2bf(acc[mi][ni][j]);
    }
  // fused chunk carry-sum: carr[chunk] = sum_r dA^{63-r} Bu_r  (fp32 accs)
  const int cu = (m0 >> 6) + wm;
#pragma unroll
  for (int ni = 0; ni < 2; ++ni) {
    int gc = wn * 32 + ni * 16 + fr;
    int p = gc & 63;
    float2 dA = dAf[p];
    float sre = 0.f, sim = 0.f;
#pragma unroll
    for (int mi = 0; mi < 4; ++mi) {
      float tr = 0.f, ti = 0.f;
#pragma unroll
      for (int j = 0; j < 4; ++j) {
        float v = acc[mi][ni][j];
        float nr = fmaf(dA.x, tr, fmaf(-dA.y, ti, v));
        float nim = fmaf(dA.x, ti, dA.y * tr);
        tr = nr; ti = nim;
      }
      float2 wg = powt[p * (GCH + 1) + 60 - g * 4 - 16 * mi];
      sre = fmaf(wg.x, tr, fmaf(-wg.y, ti, sre));
      sim = fmaf(wg.x, ti, fmaf(wg.y, tr, sim));
    }
    sre += __shfl_xor(sre, 16); sim += __shfl_xor(sim, 16);
    sre += __shfl_xor(sre, 32); sim += __shfl_xor(sim, 32);
    if (g == 0) {
      size_t crow = (size_t)cu * 128;
      if (gc < 64) { carr[crow + p] = sre;  carr[crow + 64 + p] = sim; }
      else         { carr2[crow + p] = -sim; carr2[crow + 64 + p] = sre; }
    }
  }
}

// ---------------- K3b: chunk-carry exclusive prefix scan (4 blocks, 1/seq) ----
__global__ void scan_carry_k(const float* __restrict__ carr, const float* __restrict__ carr2,
                             float* __restrict__ offc, const float2* __restrict__ powt) {
  int b = blockIdx.x;          // one block per batch sequence
  int p = threadIdx.x;         // 64 lanes
  float2 dAG = powt[p * (GCH + 1) + GCH];   // dA^G
  float rr = 0.f, ri = 0.f;
  float a0[8], b0[8], c0a[8], d0a[8];
  float a1[8], b1[8], c1a[8], d1a[8];

#define LOADB(cb, A_, B_, C_, D_)                                      \
  {                                                                     \
    _Pragma("unroll") for (int j = 0; j < 8; ++j) {                     \
      size_t crow = (size_t)(b * NCH + (cb) + j) * 128;                 \
      A_[j] = carr[crow + p]; B_[j] = carr[crow + 64 + p];              \
      C_[j] = carr2[crow + p]; D_[j] = carr2[crow + 64 + p];            \
    }                                                                   \
  }
#define STEPB(cb, A_, B_, C_, D_)                                      \
  {                                                                     \
    _Pragma("unroll") for (int j = 0; j < 8; ++j) {                     \
      size_t orow = (size_t)(b * NCH + (cb) + j) * 128;                 \
      offc[orow + p] = rr; offc[orow + 64 + p] = ri;                    \
      float er = A_[j] + C_[j], ei = B_[j] + D_[j];                     \
      float nr = fmaf(dAG.x, rr, fmaf(-dAG.y, ri, er));                 \
      float ni = fmaf(dAG.x, ri, fmaf(dAG.y, rr, ei));                  \
      rr = nr; ri = ni;                                                 \
    }                                                                   \
  }

  LOADB(0, a0, b0, c0a, d0a);
  for (int c0 = 0; c0 < NCH; c0 += 16) {
    LOADB(c0 + 8, a1, b1, c1a, d1a);
    STEPB(c0, a0, b0, c0a, d0a);
    if (c0 + 16 < NCH) LOADB(c0 + 16, a0, b0, c0a, d0a);
    STEPB(c0 + 8, a1, b1, c1a, d1a);
  }
#undef LOADB
#undef STEPB
}

// ---------------- K3c: seeded local scan (bf16 Bu in), emits bf16 h ------------
__global__ __launch_bounds__(256) void scan_emit_k(const u16* __restrict__ Bu,
                                                   const float* __restrict__ offc,
                                                   u16* __restrict__ hb,
                                                   const float2* __restrict__ dAf) {
  int unit = blockIdx.x * 4 + (threadIdx.x >> 6);   // b*NCH + c
  int p = threadIdx.x & 63;
  int b = unit >> 8, c = unit & 255;
  float2 dA = dAf[p];
  size_t base = ((size_t)b * LSEQ + (size_t)c * GCH) * 128;
  float hr = offc[(size_t)unit * 128 + p];
  float hi = offc[(size_t)unit * 128 + 64 + p];
  for (int i0 = 0; i0 < GCH; i0 += 8) {
    float br[8], bi[8];
#pragma unroll
    for (int j = 0; j < 8; ++j) {
      br[j] = bf2f(Bu[base + (size_t)(i0 + j) * 128 + p]);
      bi[j] = bf2f(Bu[base + (size_t)(i0 + j) * 128 + 64 + p]);
    }
#pragma unroll
    for (int j = 0; j < 8; ++j) {
      float nr = fmaf(dA.x, hr, fmaf(-dA.y, hi, br[j]));
      float ni = fmaf(dA.x, hi, fmaf(dA.y, hr, bi[j]));
      hr = nr; hi = ni;
      hb[base + (size_t)(i0 + j) * 128 + p] = f2bf(hr);
      hb[base + (size_t)(i0 + j) * 128 + 64 + p] = f2bf(hi);
    }
  }
}

extern "C" void kernel_launch(void* const* d_in, const int* in_sizes, int n_in,
                              void* d_out, int out_size, void* d_ws, size_t ws_size,
                              hipStream_t stream) {
  const float* x      = (const float*)d_in[0];
  const float* W_in   = (const float*)d_in[1];
  const float* W_out  = (const float*)d_in[2];
  const float* A_real = (const float*)d_in[3];
  const float* A_imag = (const float*)d_in[4];
  const float* B_re   = (const float*)d_in[5];
  const float* B_im   = (const float*)d_in[6];
  const float* C_re   = (const float*)d_in[7];
  const float* C_im   = (const float*)d_in[8];
  const float* Dv     = (const float*)d_in[9];
  const float* inv_dt = (const float*)d_in[10];

  // ---- workspace layout (bf16 buffers) ----
  u16* xb    = (u16*)d_ws;                       // N*256
  u16* u_bf  = xb + (size_t)NTOK * 256;          // N*512
  u16* sr_bf = u_bf + (size_t)NTOK * 512;        // N*512 (becomes g after K4a)
  u16* h_bf  = sr_bf + (size_t)NTOK * 512;       // N*128
  u16* WinT  = h_bf + (size_t)NTOK * 128;        // 1024*256
  u16* dBn   = WinT + 1024 * 256;                // 128*512
  u16* Ccb   = dBn + 128 * 512;                  // 512*128
  u16* WoutT = Ccb + 512 * 128;                  // 256*512

  // ---- d_out doubles as scratch (dead before final GEMM writes it) ----
  float* O    = (float*)d_out;
  u16* Bu     = (u16*)O;                  // N*128 u16 = 4194304 float-slots
  float* offc = O + 4194304;              // 1024*128
  float* carr = O + 4325376;              // 1024*128
  float* car2 = O + 4456448;              // 1024*128
  float2* powt = (float2*)(O + 4587520);  // 64*65 float2
  float2* dAf  = (float2*)(O + 4595840);  // 64 float2
  float2* fvec = (float2*)(O + 4595968);  // 64 float2

  setup_scalar_k<<<1, 64, 0, stream>>>(A_real, A_imag, inv_dt, dAf, fvec, powt);
  setup_tables_k<<<256, 256, 0, stream>>>(B_re, B_im, C_re, C_im, W_in, W_out, fvec,
                                          WinT, dBn, Ccb, WoutT);
  cvt_x_k<<<2048, 256, 0, stream>>>(x, xb);

  // K1: [u|res] = silu(x @ W_in)  (512 m-tiles x 8 col-tiles)
  k1_gemm<<<4096, 512, 0, stream>>>(xb, WinT, u_bf, sr_bf);
  // K2: Bu = u @ dB^T (bf16) + fused chunk carry
  k2_bu_carry<<<512, 512, 0, stream>>>(u_bf, dBn, Bu, carr, car2, dAf, powt);
  // K3: carry prefix scan (4 blocks) + seeded local scan -> bf16 h
  scan_carry_k<<<4, 64, 0, stream>>>(carr, car2, offc, powt);
  scan_emit_k<<<256, 256, 0, stream>>>(Bu, offc, h_bf, dAf);
  // K4a: g = (Re(h C^T) + D*u) * sres  (512 m-tiles x 2 n-tiles)
  mgemm2<2, 1, 128><<<1024, 1024, 0, stream>>>(h_bf, Ccb, u_bf, sr_bf, Dv);
  // K4b: out = g @ W_out  (512 m-tiles x 1 n-tile)
  mgemm2<3, 0, 512><<<512, 1024, 0, stream>>>(sr_bf, WoutT, O, nullptr, nullptr);
}